// Round 2
// baseline (1752.707 us; speedup 1.0000x reference)
//
#include <hip/hip_runtime.h>
#include <hip/hip_bf16.h>
#include <math.h>

#define NN 50000
#define EE 200000

typedef __bf16 bf16x8 __attribute__((ext_vector_type(8)));
typedef float f32x4 __attribute__((ext_vector_type(4)));

static __device__ __forceinline__ bf16x8 ld8(const __bf16* p) {
  return *reinterpret_cast<const bf16x8*>(p);
}

// load 8 contiguous fp32, convert to bf16x8
static __device__ __forceinline__ bf16x8 cvt8(const float* p) {
  const f32x4* q = reinterpret_cast<const f32x4*>(p);
  f32x4 a = q[0], b = q[1];
  bf16x8 r;
  r[0] = (__bf16)a[0]; r[1] = (__bf16)a[1]; r[2] = (__bf16)a[2]; r[3] = (__bf16)a[3];
  r[4] = (__bf16)b[0]; r[5] = (__bf16)b[1]; r[6] = (__bf16)b[2]; r[7] = (__bf16)b[3];
  return r;
}

static __device__ __forceinline__ bf16x8 zero8() {
  bf16x8 z;
  #pragma unroll
  for (int j = 0; j < 8; ++j) z[j] = (__bf16)0.0f;
  return z;
}

// ---------------- prep kernels ----------------

__global__ __launch_bounds__(256) void k_cvt(const float* __restrict__ src,
                                             __bf16* __restrict__ dst, int n) {
  int i = blockIdx.x * 256 + threadIdx.x;
  if (i < n) dst[i] = (__bf16)src[i];
}

__global__ __launch_bounds__(256) void k_ddst(const int* __restrict__ ei, int* __restrict__ ddst) {
  int e = blockIdx.x * 256 + threadIdx.x;
  if (e < EE) {
    int d = ei[EE + e];         // dst[e]
    ddst[e] = ei[EE + d];       // dst[dst[e]]
  }
}

// aux[e] = [edge_feat(64) | tenc(16) | zeros(16)]  (E x 96, bf16)
__global__ __launch_bounds__(256) void k_aux(const float* __restrict__ ef,
                                             const float* __restrict__ tim,
                                             const float* __restrict__ tew,
                                             const float* __restrict__ teph,
                                             __bf16* __restrict__ aux) {
  int lane = threadIdx.x & 63;
  int wv = threadIdx.x >> 6;
  int e = blockIdx.x * 4 + wv;
  float td = -tim[e];
  __bf16* row = aux + (size_t)e * 96;
  row[lane] = (__bf16)ef[(size_t)e * 64 + lane];
  if (lane < 32) {
    if (lane < 16) {
      float wt = td * tew[lane] + teph[lane];
      float v = (lane == 0) ? wt : sinf(wt);
      row[64 + lane] = (__bf16)v;
    } else {
      row[64 + lane] = (__bf16)0.0f;
    }
  }
}

// cq[n] = bq[n] + sum_t qte[t] * wq[n][256+t], qte = time_enc(0) = [phi0, sin(phi_t)]
__global__ __launch_bounds__(256) void k_cq(const float* __restrict__ wq_l,
                                            const float* __restrict__ bq_l,
                                            const float* __restrict__ teph_l,
                                            float* __restrict__ cq) {
  int n = threadIdx.x;
  float s = bq_l[n];
  for (int t = 0; t < 16; ++t) {
    float ph = teph_l[t];
    float q = (t == 0) ? ph : sinf(ph);
    s += q * wq_l[(size_t)n * 272 + 256 + t];
  }
  cq[n] = s;
}

// ---------------- h0 = [node_feat|memory] @ in_w^T + in_b ----------------

__global__ __launch_bounds__(256, 2) void k_h0(const float* __restrict__ nf,
                                               const float* __restrict__ mem,
                                               const __bf16* __restrict__ w,
                                               const float* __restrict__ bias,
                                               float* __restrict__ hf,
                                               __bf16* __restrict__ hb) {
  const int lane = threadIdx.x & 63;
  const int wv = threadIdx.x >> 6;
  const int c = lane & 15, g = lane >> 4;
  const int row0 = blockIdx.x * 64 + wv * 16;
  int rowA = row0 + c; if (rowA >= NN) rowA = NN - 1;
  const float* An = nf + (size_t)rowA * 128;
  const float* Am = mem + (size_t)rowA * 128;
  f32x4 acc[16];
  #pragma unroll
  for (int t = 0; t < 16; ++t)
    for (int r = 0; r < 4; ++r) acc[t][r] = 0.0f;

  for (int ks = 0; ks < 8; ++ks) {
    const int k = ks * 32 + g * 8;
    const float* ap = (k < 128) ? (An + k) : (Am + (k - 128));
    bf16x8 a = cvt8(ap);
    #pragma unroll
    for (int t = 0; t < 16; ++t) {
      bf16x8 b = ld8(w + (size_t)(t * 16 + c) * 256 + k);
      acc[t] = __builtin_amdgcn_mfma_f32_16x16x32_bf16(a, b, acc[t], 0, 0, 0);
    }
  }
  #pragma unroll
  for (int t = 0; t < 16; ++t) {
    const int col = t * 16 + c;
    const float bv = bias[col];
    #pragma unroll
    for (int r = 0; r < 4; ++r) {
      const int row = row0 + g * 4 + r;
      if (row < NN) {
        float x = acc[t][r] + bv;
        hf[(size_t)row * 256 + col] = x;
        hb[(size_t)row * 256 + col] = (__bf16)x;
      }
    }
  }
}

// ---------------- scores: af[e] = mean_h exp(clip(Q.K/8)) ----------------

__global__ __launch_bounds__(256, 2) void k_scores(const __bf16* __restrict__ hb,
                                                   const int* __restrict__ ei,
                                                   const int* __restrict__ ddst,
                                                   const __bf16* __restrict__ aux,
                                                   const __bf16* __restrict__ wq_l,
                                                   const __bf16* __restrict__ wk_l,
                                                   const float* __restrict__ bk_l,
                                                   const float* __restrict__ cq,
                                                   float* __restrict__ af) {
  const int lane = threadIdx.x & 63;
  const int wv = threadIdx.x >> 6;
  const int c = lane & 15, g = lane >> 4;
  const int row0 = blockIdx.x * 64 + wv * 16;
  const int eA = row0 + c;
  const int iq = ddst[eA];
  const int ik = ei[eA];          // src[e]
  const __bf16* Aq = hb + (size_t)iq * 256;
  const __bf16* Ak = hb + (size_t)ik * 256;
  const __bf16* Ax = aux + (size_t)eA * 96;

  f32x4 aq[16], ak[16];
  #pragma unroll
  for (int t = 0; t < 16; ++t)
    for (int r = 0; r < 4; ++r) { aq[t][r] = 0.0f; ak[t][r] = 0.0f; }

  // Q = h[ddst] @ wq[:, :256]^T   (row stride 272)
  for (int ks = 0; ks < 8; ++ks) {
    const int k = ks * 32 + g * 8;
    bf16x8 a = ld8(Aq + k);
    #pragma unroll
    for (int t = 0; t < 16; ++t) {
      bf16x8 b = ld8(wq_l + (size_t)(t * 16 + c) * 272 + k);
      aq[t] = __builtin_amdgcn_mfma_f32_16x16x32_bf16(a, b, aq[t], 0, 0, 0);
    }
  }
  // K main = h[src] @ wk[:, :256]^T  (row stride 336)
  for (int ks = 0; ks < 8; ++ks) {
    const int k = ks * 32 + g * 8;
    bf16x8 a = ld8(Ak + k);
    #pragma unroll
    for (int t = 0; t < 16; ++t) {
      bf16x8 b = ld8(wk_l + (size_t)(t * 16 + c) * 336 + k);
      ak[t] = __builtin_amdgcn_mfma_f32_16x16x32_bf16(a, b, ak[t], 0, 0, 0);
    }
  }
  // K aux = aux(96, zero-padded) @ wk[:, 256:336]^T
  const bf16x8 bz = zero8();
  for (int ks = 0; ks < 3; ++ks) {
    const int kk = ks * 32 + g * 8;
    bf16x8 a = ld8(Ax + kk);
    #pragma unroll
    for (int t = 0; t < 16; ++t) {
      bf16x8 b = (kk < 80) ? ld8(wk_l + (size_t)(t * 16 + c) * 336 + 256 + kk) : bz;
      ak[t] = __builtin_amdgcn_mfma_f32_16x16x32_bf16(a, b, ak[t], 0, 0, 0);
    }
  }

  // per-head dot: same (lane, reg, tile) holds matching Q,K elements
  float s[4][4];
  #pragma unroll
  for (int h = 0; h < 4; ++h)
    for (int r = 0; r < 4; ++r) s[h][r] = 0.0f;
  #pragma unroll
  for (int t = 0; t < 16; ++t) {
    const float cqv = cq[t * 16 + c];
    const float bkv = bk_l[t * 16 + c];
    #pragma unroll
    for (int r = 0; r < 4; ++r)
      s[t >> 2][r] += (aq[t][r] + cqv) * (ak[t][r] + bkv);
  }
  #pragma unroll
  for (int m = 1; m < 16; m <<= 1)
    #pragma unroll
    for (int h = 0; h < 4; ++h)
      for (int r = 0; r < 4; ++r) s[h][r] += __shfl_xor(s[h][r], m, 64);

  if (c == 0) {
    #pragma unroll
    for (int r = 0; r < 4; ++r) {
      const int e = row0 + g * 4 + r;
      float a0 = 0.0f;
      #pragma unroll
      for (int h = 0; h < 4; ++h) {
        float sc = s[h][r] * 0.125f;            // / sqrt(64)
        sc = fminf(5.0f, fmaxf(-5.0f, sc));
        a0 += expf(sc);
      }
      af[e] = a0 * 0.25f;
    }
  }
}

// ---------------- V = msg @ wv^T + bv, scatter V*af into agg/nrm ----------------

__global__ __launch_bounds__(256, 2) void k_vscat(const __bf16* __restrict__ hb,
                                                  const int* __restrict__ ei,
                                                  const __bf16* __restrict__ aux,
                                                  const __bf16* __restrict__ wv_l,
                                                  const float* __restrict__ bv_l,
                                                  const float* __restrict__ af,
                                                  float* __restrict__ agg,
                                                  float* __restrict__ nrm) {
  const int lane = threadIdx.x & 63;
  const int wv = threadIdx.x >> 6;
  const int c = lane & 15, g = lane >> 4;
  const int row0 = blockIdx.x * 64 + wv * 16;
  const int eA = row0 + c;
  const int ik = ei[eA];
  const __bf16* Ak = hb + (size_t)ik * 256;
  const __bf16* Ax = aux + (size_t)eA * 96;

  f32x4 acc[16];
  #pragma unroll
  for (int t = 0; t < 16; ++t)
    for (int r = 0; r < 4; ++r) acc[t][r] = 0.0f;

  for (int ks = 0; ks < 8; ++ks) {
    const int k = ks * 32 + g * 8;
    bf16x8 a = ld8(Ak + k);
    #pragma unroll
    for (int t = 0; t < 16; ++t) {
      bf16x8 b = ld8(wv_l + (size_t)(t * 16 + c) * 336 + k);
      acc[t] = __builtin_amdgcn_mfma_f32_16x16x32_bf16(a, b, acc[t], 0, 0, 0);
    }
  }
  const bf16x8 bz = zero8();
  for (int ks = 0; ks < 3; ++ks) {
    const int kk = ks * 32 + g * 8;
    bf16x8 a = ld8(Ax + kk);
    #pragma unroll
    for (int t = 0; t < 16; ++t) {
      bf16x8 b = (kk < 80) ? ld8(wv_l + (size_t)(t * 16 + c) * 336 + 256 + kk) : bz;
      acc[t] = __builtin_amdgcn_mfma_f32_16x16x32_bf16(a, b, acc[t], 0, 0, 0);
    }
  }

  float afv[4];
  int dd[4];
  #pragma unroll
  for (int r = 0; r < 4; ++r) {
    const int e = row0 + g * 4 + r;
    afv[r] = af[e];
    dd[r] = ei[EE + e];    // dst[e]
  }
  #pragma unroll
  for (int t = 0; t < 16; ++t) {
    const int col = t * 16 + c;
    const float bvv = bv_l[col];
    #pragma unroll
    for (int r = 0; r < 4; ++r) {
      float v = (acc[t][r] + bvv) * afv[r];
      atomicAdd(&agg[(size_t)dd[r] * 256 + col], v);
    }
  }
  if (c == 0) {
    #pragma unroll
    for (int r = 0; r < 4; ++r) atomicAdd(&nrm[dd[r]], afv[r]);
  }
}

// ---------------- per-node: h = LN(h + LN(agg/nrm)*aw+ab)*lw+lb ----------------

__global__ __launch_bounds__(256) void k_norm(float* __restrict__ hf,
                                              __bf16* __restrict__ hb,
                                              const float* __restrict__ agg,
                                              const float* __restrict__ nrm,
                                              const float* __restrict__ aw,
                                              const float* __restrict__ ab,
                                              const float* __restrict__ lw,
                                              const float* __restrict__ lb) {
  const int lane = threadIdx.x & 63;
  const int wv = threadIdx.x >> 6;
  const int node = blockIdx.x * 4 + wv;
  const size_t base = (size_t)node * 256 + lane * 4;
  f32x4 ag = *reinterpret_cast<const f32x4*>(agg + base);
  const float inv = 1.0f / (nrm[node] + 1e-8f);
  float x[4], y[4];
  float s = 0.0f;
  #pragma unroll
  for (int j = 0; j < 4; ++j) { x[j] = ag[j] * inv; s += x[j]; }
  #pragma unroll
  for (int m = 1; m < 64; m <<= 1) s += __shfl_xor(s, m, 64);
  const float mean = s * (1.0f / 256.0f);
  float v = 0.0f;
  #pragma unroll
  for (int j = 0; j < 4; ++j) { float d = x[j] - mean; v += d * d; }
  #pragma unroll
  for (int m = 1; m < 64; m <<= 1) v += __shfl_xor(v, m, 64);
  const float rstd = rsqrtf(v * (1.0f / 256.0f) + 1e-5f);

  f32x4 hrow = *reinterpret_cast<const f32x4*>(hf + base);
  float s2 = 0.0f;
  #pragma unroll
  for (int j = 0; j < 4; ++j) {
    const int k = lane * 4 + j;
    float hn = (x[j] - mean) * rstd * aw[k] + ab[k];
    y[j] = hrow[j] + hn;
    s2 += y[j];
  }
  #pragma unroll
  for (int m = 1; m < 64; m <<= 1) s2 += __shfl_xor(s2, m, 64);
  const float mean2 = s2 * (1.0f / 256.0f);
  float v2 = 0.0f;
  #pragma unroll
  for (int j = 0; j < 4; ++j) { float d = y[j] - mean2; v2 += d * d; }
  #pragma unroll
  for (int m = 1; m < 64; m <<= 1) v2 += __shfl_xor(v2, m, 64);
  const float rstd2 = rsqrtf(v2 * (1.0f / 256.0f) + 1e-5f);
  #pragma unroll
  for (int j = 0; j < 4; ++j) {
    const int k = lane * 4 + j;
    float o = (y[j] - mean2) * rstd2 * lw[k] + lb[k];
    hf[base + j] = o;
    hb[base + j] = (__bf16)o;
  }
}

// ---------------- out = gelu(h @ out_w^T + out_b) ----------------

__global__ __launch_bounds__(256, 2) void k_out(const __bf16* __restrict__ hb,
                                                const __bf16* __restrict__ ow,
                                                const float* __restrict__ ob,
                                                float* __restrict__ out) {
  const int lane = threadIdx.x & 63;
  const int wv = threadIdx.x >> 6;
  const int c = lane & 15, g = lane >> 4;
  const int row0 = blockIdx.x * 64 + wv * 16;
  int rowA = row0 + c; if (rowA >= NN) rowA = NN - 1;
  const __bf16* A = hb + (size_t)rowA * 256;
  f32x4 acc[4];
  #pragma unroll
  for (int t = 0; t < 4; ++t)
    for (int r = 0; r < 4; ++r) acc[t][r] = 0.0f;
  for (int ks = 0; ks < 8; ++ks) {
    const int k = ks * 32 + g * 8;
    bf16x8 a = ld8(A + k);
    #pragma unroll
    for (int t = 0; t < 4; ++t) {
      bf16x8 b = ld8(ow + (size_t)(t * 16 + c) * 256 + k);
      acc[t] = __builtin_amdgcn_mfma_f32_16x16x32_bf16(a, b, acc[t], 0, 0, 0);
    }
  }
  #pragma unroll
  for (int t = 0; t < 4; ++t) {
    const int col = t * 16 + c;
    const float bv = ob[col];
    #pragma unroll
    for (int r = 0; r < 4; ++r) {
      const int row = row0 + g * 4 + r;
      if (row < NN) {
        float x = acc[t][r] + bv;
        float gy = 0.5f * x * (1.0f + erff(x * 0.70710678118654752f));
        out[(size_t)row * 64 + col] = gy;
      }
    }
  }
}

// ---------------- launcher ----------------

extern "C" void kernel_launch(void* const* d_in, const int* in_sizes, int n_in,
                              void* d_out, int out_size, void* d_ws, size_t ws_size,
                              hipStream_t stream) {
  (void)in_sizes; (void)n_in; (void)out_size; (void)ws_size;
  const float* nf   = (const float*)d_in[0];
  const float* mem  = (const float*)d_in[1];
  const int*   ei   = (const int*)d_in[2];
  const float* ef   = (const float*)d_in[3];
  const float* tim  = (const float*)d_in[4];
  const float* inw  = (const float*)d_in[5];
  const float* inb  = (const float*)d_in[6];
  const float* tew  = (const float*)d_in[7];
  const float* teph = (const float*)d_in[8];
  const float* wq   = (const float*)d_in[9];
  const float* wqb  = (const float*)d_in[10];
  const float* wk   = (const float*)d_in[11];
  const float* wkb  = (const float*)d_in[12];
  const float* wvw  = (const float*)d_in[13];
  const float* wvb  = (const float*)d_in[14];
  const float* alw  = (const float*)d_in[15];
  const float* alb  = (const float*)d_in[16];
  const float* lnw  = (const float*)d_in[17];
  const float* lnb  = (const float*)d_in[18];
  const float* ow   = (const float*)d_in[19];
  const float* ob   = (const float*)d_in[20];
  float* out = (float*)d_out;

  char* ws = (char*)d_ws;
  float*  hf   = (float*) (ws + 0);            // N*256 f32   = 51,200,000 B
  __bf16* hb   = (__bf16*)(ws + 51200000);     // N*256 bf16  = 25,600,000 B
  float*  agg  = (float*) (ws + 76800000);     // N*256 f32   = 51,200,000 B
  float*  nrm  = (float*) (ws + 128000000);    // N f32       =    200,000 B
  __bf16* aux  = (__bf16*)(ws + 128200192);    // E*96 bf16   = 38,400,000 B
  int*    ddst = (int*)   (ws + 166600192);    // E int       =    800,000 B
  float*  af   = (float*) (ws + 167400192);    // E f32       =    800,000 B
  float*  cq   = (float*) (ws + 168200192);    // 256 f32 (+pad to 1024 B)
  __bf16* cinw = (__bf16*)(ws + 168201216);    // 65,536 bf16  = 131,072 B
  __bf16* cwq  = (__bf16*)(ws + 168332288);    // 139,264 bf16 = 278,528 B
  __bf16* cwk  = (__bf16*)(ws + 168610816);    // 172,032 bf16 = 344,064 B
  __bf16* cwv  = (__bf16*)(ws + 168954880);    // 172,032 bf16 = 344,064 B
  __bf16* cow  = (__bf16*)(ws + 169298944);    // 16,384 bf16  = 32,768 B

  // weight fp32 -> bf16 conversions
  k_cvt<<<(65536 + 255) / 256, 256, 0, stream>>>(inw, cinw, 65536);
  k_cvt<<<(139264 + 255) / 256, 256, 0, stream>>>(wq, cwq, 139264);
  k_cvt<<<(172032 + 255) / 256, 256, 0, stream>>>(wk, cwk, 172032);
  k_cvt<<<(172032 + 255) / 256, 256, 0, stream>>>(wvw, cwv, 172032);
  k_cvt<<<(16384 + 255) / 256, 256, 0, stream>>>(ow, cow, 16384);

  k_ddst<<<(EE + 255) / 256, 256, 0, stream>>>(ei, ddst);
  k_h0<<<(NN + 63) / 64, 256, 0, stream>>>(nf, mem, cinw, inb, hf, hb);

  for (int l = 0; l < 2; ++l) {
    const __bf16* wq_l = cwq + (size_t)l * 256 * 272;
    const __bf16* wk_l = cwk + (size_t)l * 256 * 336;
    const __bf16* wv_l = cwv + (size_t)l * 256 * 336;
    k_aux<<<EE / 4, 256, 0, stream>>>(ef, tim, tew + l * 16, teph + l * 16, aux);
    k_cq<<<1, 256, 0, stream>>>(wq + (size_t)l * 256 * 272, wqb + l * 256, teph + l * 16, cq);
    k_scores<<<EE / 64, 256, 0, stream>>>(hb, ei, ddst, aux, wq_l, wk_l, wkb + l * 256, cq, af);
    hipMemsetAsync(agg, 0, (size_t)51400000, stream);   // agg + nrm contiguous
    k_vscat<<<EE / 64, 256, 0, stream>>>(hb, ei, aux, wv_l, wvb + l * 256, af, agg, nrm);
    k_norm<<<NN / 4, 256, 0, stream>>>(hf, hb, agg, nrm, alw + l * 256, alb + l * 256,
                                       lnw + l * 256, lnb + l * 256);
  }
  k_out<<<(NN + 63) / 64, 256, 0, stream>>>(hb, cow, ob, out);
}

// Round 3
// 1168.730 us; speedup vs baseline: 1.4997x; 1.4997x over previous
//
#include <hip/hip_runtime.h>
#include <hip/hip_bf16.h>
#include <math.h>

#define NN 50000
#define EE 200000

typedef __bf16 bf16x8 __attribute__((ext_vector_type(8)));
typedef __bf16 bf16x4 __attribute__((ext_vector_type(4)));
typedef __bf16 bf16x2 __attribute__((ext_vector_type(2)));
typedef float f32x4 __attribute__((ext_vector_type(4)));

static __device__ __forceinline__ bf16x8 ld8(const __bf16* p) {
  return *reinterpret_cast<const bf16x8*>(p);
}
static __device__ __forceinline__ bf16x4 ld4(const __bf16* p) {
  return *reinterpret_cast<const bf16x4*>(p);
}
static __device__ __forceinline__ bf16x8 cvt8(const float* p) {
  const f32x4* q = reinterpret_cast<const f32x4*>(p);
  f32x4 a = q[0], b = q[1];
  bf16x8 r;
  r[0] = (__bf16)a[0]; r[1] = (__bf16)a[1]; r[2] = (__bf16)a[2]; r[3] = (__bf16)a[3];
  r[4] = (__bf16)b[0]; r[5] = (__bf16)b[1]; r[6] = (__bf16)b[2]; r[7] = (__bf16)b[3];
  return r;
}
static __device__ __forceinline__ bf16x8 zero8() {
  bf16x8 z;
  #pragma unroll
  for (int j = 0; j < 8; ++j) z[j] = (__bf16)0.0f;
  return z;
}

// ---------------- prep kernels ----------------

__global__ __launch_bounds__(256) void k_cvt(const float* __restrict__ src,
                                             __bf16* __restrict__ dst, int n) {
  int i = blockIdx.x * 256 + threadIdx.x;
  if (i < n) dst[i] = (__bf16)src[i];
}

__global__ __launch_bounds__(256) void k_ddst(const int* __restrict__ ei, int* __restrict__ ddst) {
  int e = blockIdx.x * 256 + threadIdx.x;
  if (e < EE) {
    int d = ei[EE + e];
    ddst[e] = ei[EE + d];   // dst[dst[e]]
  }
}

// CSR build: histogram over dst
__global__ __launch_bounds__(256) void k_hist(const int* __restrict__ ei, int* __restrict__ cnt) {
  int e = blockIdx.x * 256 + threadIdx.x;
  if (e < EE) atomicAdd(&cnt[ei[EE + e]], 1);
}

// single-block exclusive scan: cnt(in wp) -> rowptr, wp reset to bucket write starts
__global__ __launch_bounds__(1024) void k_scan(int* __restrict__ wp, int* __restrict__ rowptr) {
  __shared__ int part[1024];
  const int t = threadIdx.x;
  const int CH = 49;                      // 1024*49 = 50176 >= NN
  int lo = t * CH, hi = lo + CH; if (hi > NN) hi = NN; if (lo > NN) lo = NN;
  int s = 0;
  for (int i = lo; i < hi; ++i) s += wp[i];
  part[t] = s;
  __syncthreads();
  for (int off = 1; off < 1024; off <<= 1) {
    int v = (t >= off) ? part[t - off] : 0;
    __syncthreads();
    part[t] += v;
    __syncthreads();
  }
  int run = (t == 0) ? 0 : part[t - 1];
  for (int i = lo; i < hi; ++i) {
    int c = wp[i];
    rowptr[i] = run;
    wp[i] = run;
    run += c;
  }
  if (t == 1023) rowptr[NN] = part[1023];
}

__global__ __launch_bounds__(256) void k_fill(const int* __restrict__ ei,
                                              int* __restrict__ wp,
                                              int* __restrict__ bucket) {
  int e = blockIdx.x * 256 + threadIdx.x;
  if (e < EE) {
    int d = ei[EE + e];
    int pos = atomicAdd(&wp[d], 1);
    bucket[pos] = e;
  }
}

// aux[e] = [edge_feat(64) | tenc(16) | zeros(16)]  (E x 96, bf16)
__global__ __launch_bounds__(256) void k_aux(const float* __restrict__ ef,
                                             const float* __restrict__ tim,
                                             const float* __restrict__ tew,
                                             const float* __restrict__ teph,
                                             __bf16* __restrict__ aux) {
  int lane = threadIdx.x & 63;
  int wv = threadIdx.x >> 6;
  int e = blockIdx.x * 4 + wv;
  float td = -tim[e];
  __bf16* row = aux + (size_t)e * 96;
  row[lane] = (__bf16)ef[(size_t)e * 64 + lane];
  if (lane < 32) {
    if (lane < 16) {
      float wt = td * tew[lane] + teph[lane];
      float v = (lane == 0) ? wt : sinf(wt);
      row[64 + lane] = (__bf16)v;
    } else {
      row[64 + lane] = (__bf16)0.0f;
    }
  }
}

// cq[n] = bq[n] + sum_t qte[t]*wq[n][256+t]
__global__ __launch_bounds__(256) void k_cq(const float* __restrict__ wq_l,
                                            const float* __restrict__ bq_l,
                                            const float* __restrict__ teph_l,
                                            float* __restrict__ cq) {
  int n = threadIdx.x;
  float s = bq_l[n];
  for (int t = 0; t < 16; ++t) {
    float ph = teph_l[t];
    float q = (t == 0) ? ph : sinf(ph);
    s += q * wq_l[(size_t)n * 272 + 256 + t];
  }
  cq[n] = s;
}

// ---------------- h0 = [node_feat|memory] @ in_w^T + in_b  -> hb (bf16) ----------------

__global__ __launch_bounds__(256, 2) void k_h0(const float* __restrict__ nf,
                                               const float* __restrict__ mem,
                                               const __bf16* __restrict__ w,
                                               const float* __restrict__ bias,
                                               __bf16* __restrict__ hb) {
  const int lane = threadIdx.x & 63;
  const int wv = threadIdx.x >> 6;
  const int c = lane & 15, g = lane >> 4;
  const int row0 = blockIdx.x * 64 + wv * 16;
  int rowA = row0 + c; if (rowA >= NN) rowA = NN - 1;
  const float* An = nf + (size_t)rowA * 128;
  const float* Am = mem + (size_t)rowA * 128;
  f32x4 acc[16];
  #pragma unroll
  for (int t = 0; t < 16; ++t)
    for (int r = 0; r < 4; ++r) acc[t][r] = 0.0f;

  for (int ks = 0; ks < 8; ++ks) {
    const int k = ks * 32 + g * 8;
    const float* ap = (k < 128) ? (An + k) : (Am + (k - 128));
    bf16x8 a = cvt8(ap);
    #pragma unroll
    for (int t = 0; t < 16; ++t) {
      bf16x8 b = ld8(w + (size_t)(t * 16 + c) * 256 + k);
      acc[t] = __builtin_amdgcn_mfma_f32_16x16x32_bf16(a, b, acc[t], 0, 0, 0);
    }
  }
  #pragma unroll
  for (int t = 0; t < 16; ++t) {
    const int col = t * 16 + c;
    const float bv = bias[col];
    #pragma unroll
    for (int r = 0; r < 4; ++r) {
      const int row = row0 + g * 4 + r;
      if (row < NN) hb[(size_t)row * 256 + col] = (__bf16)(acc[t][r] + bv);
    }
  }
}

// ---------------- Qn = h@Wq[:,:256]^T + cq ; Kn = h@Wk[:,:256]^T + bk ----------------

__global__ __launch_bounds__(256, 2) void k_qkn(const __bf16* __restrict__ hb,
                                                const __bf16* __restrict__ wq_l,
                                                const __bf16* __restrict__ wk_l,
                                                const float* __restrict__ cq,
                                                const float* __restrict__ bk_l,
                                                __bf16* __restrict__ Qn,
                                                __bf16* __restrict__ Kn) {
  const int lane = threadIdx.x & 63;
  const int wv = threadIdx.x >> 6;
  const int c = lane & 15, g = lane >> 4;
  const int row0 = blockIdx.x * 64 + wv * 16;
  int rowA = row0 + c; if (rowA >= NN) rowA = NN - 1;
  const __bf16* A = hb + (size_t)rowA * 256;

  f32x4 aq[16], ak[16];
  #pragma unroll
  for (int t = 0; t < 16; ++t)
    for (int r = 0; r < 4; ++r) { aq[t][r] = 0.0f; ak[t][r] = 0.0f; }

  for (int ks = 0; ks < 8; ++ks) {
    const int k = ks * 32 + g * 8;
    bf16x8 a = ld8(A + k);
    #pragma unroll
    for (int t = 0; t < 16; ++t) {
      bf16x8 bq = ld8(wq_l + (size_t)(t * 16 + c) * 272 + k);
      aq[t] = __builtin_amdgcn_mfma_f32_16x16x32_bf16(a, bq, aq[t], 0, 0, 0);
    }
    #pragma unroll
    for (int t = 0; t < 16; ++t) {
      bf16x8 bk = ld8(wk_l + (size_t)(t * 16 + c) * 336 + k);
      ak[t] = __builtin_amdgcn_mfma_f32_16x16x32_bf16(a, bk, ak[t], 0, 0, 0);
    }
  }
  #pragma unroll
  for (int t = 0; t < 16; ++t) {
    const int col = t * 16 + c;
    const float cqv = cq[col];
    const float bkv = bk_l[col];
    #pragma unroll
    for (int r = 0; r < 4; ++r) {
      const int row = row0 + g * 4 + r;
      if (row < NN) {
        Qn[(size_t)row * 256 + col] = (__bf16)(aq[t][r] + cqv);
        Kn[(size_t)row * 256 + col] = (__bf16)(ak[t][r] + bkv);
      }
    }
  }
}

// ---------------- fused per-edge scores ----------------
// P^T tile via MFMA (A = Wk_aux rows as m, B = aux rows as n=edge), then
// lane-local dot with gathered Qn[ddst] / Kn[src] rows, exp, af.

__global__ __launch_bounds__(256, 2) void k_score(const __bf16* __restrict__ aux,
                                                  const __bf16* __restrict__ wk_l,
                                                  const __bf16* __restrict__ Qn,
                                                  const __bf16* __restrict__ Kn,
                                                  const int* __restrict__ ei,
                                                  const int* __restrict__ ddst,
                                                  float* __restrict__ af) {
  const int lane = threadIdx.x & 63;
  const int wv = threadIdx.x >> 6;
  const int c = lane & 15, g = lane >> 4;
  const int row0 = blockIdx.x * 64 + wv * 16;
  const int e = row0 + c;                 // this lane's edge (n index)

  f32x4 acc[16];
  #pragma unroll
  for (int t = 0; t < 16; ++t)
    for (int r = 0; r < 4; ++r) acc[t][r] = 0.0f;

  // P^T[tile t]: D[m][n] = sum_k Wk[t*16+m][256+k] * aux[e_n][k], k in [0,96)
  const bf16x8 bz = zero8();
  const __bf16* auxr = aux + (size_t)e * 96;
  for (int ks = 0; ks < 3; ++ks) {
    const int kk = ks * 32 + g * 8;
    bf16x8 b = ld8(auxr + kk);            // B[k][n=e], zeros beyond 80 pre-stored
    #pragma unroll
    for (int t = 0; t < 16; ++t) {
      bf16x8 a = (kk < 80) ? ld8(wk_l + (size_t)(t * 16 + c) * 336 + 256 + kk) : bz;
      acc[t] = __builtin_amdgcn_mfma_f32_16x16x32_bf16(a, b, acc[t], 0, 0, 0);
    }
  }
  // acc[t][r] = P[e][t*16 + g*4 + r]

  const int iq = ddst[e];
  const int is = ei[e];
  const __bf16* Qr = Qn + (size_t)iq * 256;
  const __bf16* Kr = Kn + (size_t)is * 256;

  float sh[4] = {0.0f, 0.0f, 0.0f, 0.0f};
  #pragma unroll
  for (int t = 0; t < 16; ++t) {
    bf16x4 qv = ld4(Qr + t * 16 + g * 4);
    bf16x4 kv = ld4(Kr + t * 16 + g * 4);
    #pragma unroll
    for (int r = 0; r < 4; ++r)
      sh[t >> 2] += (float)qv[r] * ((float)kv[r] + acc[t][r]);
  }
  // reduce over g (lanes with same c): xor 16, 32
  #pragma unroll
  for (int h = 0; h < 4; ++h) {
    sh[h] += __shfl_xor(sh[h], 16, 64);
    sh[h] += __shfl_xor(sh[h], 32, 64);
  }
  float a0 = 0.0f;
  #pragma unroll
  for (int h = 0; h < 4; ++h) {
    float sc = sh[h] * 0.125f;
    sc = fminf(5.0f, fmaxf(-5.0f, sc));
    a0 += expf(sc);
  }
  if (g == 0) af[e] = a0 * 0.25f;
}

// ---------------- CSR aggregate: maggH/maggX (normalized, bf16), sfac ----------------

__global__ __launch_bounds__(256, 4) void k_magg(const __bf16* __restrict__ hb,
                                                 const __bf16* __restrict__ aux,
                                                 const int* __restrict__ ei,
                                                 const int* __restrict__ rowptr,
                                                 const int* __restrict__ bucket,
                                                 const float* __restrict__ af,
                                                 __bf16* __restrict__ maggH,
                                                 __bf16* __restrict__ maggX,
                                                 float* __restrict__ sfac) {
  const int lane = threadIdx.x & 63;
  const int wv = threadIdx.x >> 6;
  const int node = blockIdx.x * 4 + wv;
  const int beg = rowptr[node], end = rowptr[node + 1];

  float aH[4] = {0, 0, 0, 0};
  float aX[2] = {0, 0};
  float nrm = 0.0f;
  for (int i = beg; i < end; ++i) {
    const int e = bucket[i];
    const float a = af[e];
    const int s = ei[e];                       // src
    bf16x4 hv = ld4(hb + (size_t)s * 256 + lane * 4);
    #pragma unroll
    for (int j = 0; j < 4; ++j) aH[j] += a * (float)hv[j];
    if (lane < 48) {
      bf16x2 xv = *reinterpret_cast<const bf16x2*>(aux + (size_t)e * 96 + lane * 2);
      aX[0] += a * (float)xv[0];
      aX[1] += a * (float)xv[1];
    }
    nrm += a;
  }
  const float inv = 1.0f / (nrm + 1e-8f);
  bf16x4 oh;
  #pragma unroll
  for (int j = 0; j < 4; ++j) oh[j] = (__bf16)(aH[j] * inv);
  *reinterpret_cast<bf16x4*>(maggH + (size_t)node * 256 + lane * 4) = oh;
  if (lane < 48) {
    bf16x2 ox;
    ox[0] = (__bf16)(aX[0] * inv);
    ox[1] = (__bf16)(aX[1] * inv);
    *reinterpret_cast<bf16x2*>(maggX + (size_t)node * 96 + lane * 2) = ox;
  }
  if (lane == 0) sfac[node] = nrm * inv;
}

// ---------------- agg = maggH@Wv[:,:256]^T + maggX@Wv[:,256:]^T + sfac*bv ----------------

__global__ __launch_bounds__(256, 2) void k_vgemm(const __bf16* __restrict__ maggH,
                                                  const __bf16* __restrict__ maggX,
                                                  const float* __restrict__ sfac,
                                                  const __bf16* __restrict__ wv_l,
                                                  const float* __restrict__ bv_l,
                                                  float* __restrict__ agg) {
  const int lane = threadIdx.x & 63;
  const int wv = threadIdx.x >> 6;
  const int c = lane & 15, g = lane >> 4;
  const int row0 = blockIdx.x * 64 + wv * 16;
  int rowA = row0 + c; if (rowA >= NN) rowA = NN - 1;
  const __bf16* AH = maggH + (size_t)rowA * 256;
  const __bf16* AX = maggX + (size_t)rowA * 96;

  f32x4 acc[16];
  #pragma unroll
  for (int t = 0; t < 16; ++t)
    for (int r = 0; r < 4; ++r) acc[t][r] = 0.0f;

  for (int ks = 0; ks < 8; ++ks) {
    const int k = ks * 32 + g * 8;
    bf16x8 a = ld8(AH + k);
    #pragma unroll
    for (int t = 0; t < 16; ++t) {
      bf16x8 b = ld8(wv_l + (size_t)(t * 16 + c) * 336 + k);
      acc[t] = __builtin_amdgcn_mfma_f32_16x16x32_bf16(a, b, acc[t], 0, 0, 0);
    }
  }
  const bf16x8 bz = zero8();
  for (int ks = 0; ks < 3; ++ks) {
    const int kk = ks * 32 + g * 8;
    bf16x8 a = ld8(AX + kk);
    #pragma unroll
    for (int t = 0; t < 16; ++t) {
      bf16x8 b = (kk < 80) ? ld8(wv_l + (size_t)(t * 16 + c) * 336 + 256 + kk) : bz;
      acc[t] = __builtin_amdgcn_mfma_f32_16x16x32_bf16(a, b, acc[t], 0, 0, 0);
    }
  }

  float sf[4];
  #pragma unroll
  for (int r = 0; r < 4; ++r) {
    int row = row0 + g * 4 + r; if (row >= NN) row = NN - 1;
    sf[r] = sfac[row];
  }
  #pragma unroll
  for (int t = 0; t < 16; ++t) {
    const int col = t * 16 + c;
    const float bvv = bv_l[col];
    #pragma unroll
    for (int r = 0; r < 4; ++r) {
      const int row = row0 + g * 4 + r;
      if (row < NN) agg[(size_t)row * 256 + col] = acc[t][r] + sf[r] * bvv;
    }
  }
}

// ---------------- per-node: h = LN(h + LN(x)*aw+ab)*lw+lb  (x pre-normalized) ----------------

__global__ __launch_bounds__(256) void k_norm(__bf16* __restrict__ hb,
                                              const float* __restrict__ agg,
                                              const float* __restrict__ aw,
                                              const float* __restrict__ ab,
                                              const float* __restrict__ lw,
                                              const float* __restrict__ lb) {
  const int lane = threadIdx.x & 63;
  const int wv = threadIdx.x >> 6;
  const int node = blockIdx.x * 4 + wv;
  const size_t base = (size_t)node * 256 + lane * 4;
  f32x4 x4 = *reinterpret_cast<const f32x4*>(agg + base);
  float x[4], y[4];
  float s = 0.0f;
  #pragma unroll
  for (int j = 0; j < 4; ++j) { x[j] = x4[j]; s += x[j]; }
  #pragma unroll
  for (int m = 1; m < 64; m <<= 1) s += __shfl_xor(s, m, 64);
  const float mean = s * (1.0f / 256.0f);
  float v = 0.0f;
  #pragma unroll
  for (int j = 0; j < 4; ++j) { float d = x[j] - mean; v += d * d; }
  #pragma unroll
  for (int m = 1; m < 64; m <<= 1) v += __shfl_xor(v, m, 64);
  const float rstd = rsqrtf(v * (1.0f / 256.0f) + 1e-5f);

  bf16x4 hv = *reinterpret_cast<const bf16x4*>(hb + base);
  float s2 = 0.0f;
  #pragma unroll
  for (int j = 0; j < 4; ++j) {
    const int k = lane * 4 + j;
    float hn = (x[j] - mean) * rstd * aw[k] + ab[k];
    y[j] = (float)hv[j] + hn;
    s2 += y[j];
  }
  #pragma unroll
  for (int m = 1; m < 64; m <<= 1) s2 += __shfl_xor(s2, m, 64);
  const float mean2 = s2 * (1.0f / 256.0f);
  float v2 = 0.0f;
  #pragma unroll
  for (int j = 0; j < 4; ++j) { float d = y[j] - mean2; v2 += d * d; }
  #pragma unroll
  for (int m = 1; m < 64; m <<= 1) v2 += __shfl_xor(v2, m, 64);
  const float rstd2 = rsqrtf(v2 * (1.0f / 256.0f) + 1e-5f);
  bf16x4 o;
  #pragma unroll
  for (int j = 0; j < 4; ++j) {
    const int k = lane * 4 + j;
    o[j] = (__bf16)((y[j] - mean2) * rstd2 * lw[k] + lb[k]);
  }
  *reinterpret_cast<bf16x4*>(hb + base) = o;
}

// ---------------- out = gelu(h @ out_w^T + out_b) ----------------

__global__ __launch_bounds__(256, 2) void k_out(const __bf16* __restrict__ hb,
                                                const __bf16* __restrict__ ow,
                                                const float* __restrict__ ob,
                                                float* __restrict__ out) {
  const int lane = threadIdx.x & 63;
  const int wv = threadIdx.x >> 6;
  const int c = lane & 15, g = lane >> 4;
  const int row0 = blockIdx.x * 64 + wv * 16;
  int rowA = row0 + c; if (rowA >= NN) rowA = NN - 1;
  const __bf16* A = hb + (size_t)rowA * 256;
  f32x4 acc[4];
  #pragma unroll
  for (int t = 0; t < 4; ++t)
    for (int r = 0; r < 4; ++r) acc[t][r] = 0.0f;
  for (int ks = 0; ks < 8; ++ks) {
    const int k = ks * 32 + g * 8;
    bf16x8 a = ld8(A + k);
    #pragma unroll
    for (int t = 0; t < 4; ++t) {
      bf16x8 b = ld8(ow + (size_t)(t * 16 + c) * 256 + k);
      acc[t] = __builtin_amdgcn_mfma_f32_16x16x32_bf16(a, b, acc[t], 0, 0, 0);
    }
  }
  #pragma unroll
  for (int t = 0; t < 4; ++t) {
    const int col = t * 16 + c;
    const float bv = ob[col];
    #pragma unroll
    for (int r = 0; r < 4; ++r) {
      const int row = row0 + g * 4 + r;
      if (row < NN) {
        float x = acc[t][r] + bv;
        out[(size_t)row * 64 + col] = 0.5f * x * (1.0f + erff(x * 0.70710678118654752f));
      }
    }
  }
}

// ---------------- launcher ----------------

extern "C" void kernel_launch(void* const* d_in, const int* in_sizes, int n_in,
                              void* d_out, int out_size, void* d_ws, size_t ws_size,
                              hipStream_t stream) {
  (void)in_sizes; (void)n_in; (void)out_size; (void)ws_size;
  const float* nf   = (const float*)d_in[0];
  const float* mem  = (const float*)d_in[1];
  const int*   ei   = (const int*)d_in[2];
  const float* ef   = (const float*)d_in[3];
  const float* tim  = (const float*)d_in[4];
  const float* inw  = (const float*)d_in[5];
  const float* inb  = (const float*)d_in[6];
  const float* tew  = (const float*)d_in[7];
  const float* teph = (const float*)d_in[8];
  const float* wq   = (const float*)d_in[9];
  const float* wqb  = (const float*)d_in[10];
  const float* wk   = (const float*)d_in[11];
  const float* wkb  = (const float*)d_in[12];
  const float* wvw  = (const float*)d_in[13];
  const float* wvb  = (const float*)d_in[14];
  const float* alw  = (const float*)d_in[15];
  const float* alb  = (const float*)d_in[16];
  const float* lnw  = (const float*)d_in[17];
  const float* lnb  = (const float*)d_in[18];
  const float* ow   = (const float*)d_in[19];
  const float* ob   = (const float*)d_in[20];
  float* out = (float*)d_out;

  char* ws = (char*)d_ws;
  __bf16* hb    = (__bf16*)(ws + 0);            // N*256 bf16  = 25,600,000
  __bf16* aux   = (__bf16*)(ws + 25600000);     // E*96 bf16   = 38,400,000
  // union region: {Qn, Kn} before k_vgemm; agg after (stream-ordered, disjoint in time)
  __bf16* Qn    = (__bf16*)(ws + 64000000);     // N*256 bf16  = 25,600,000
  __bf16* Kn    = (__bf16*)(ws + 89600000);     // N*256 bf16  = 25,600,000
  float*  agg   = (float*) (ws + 64000000);     // N*256 f32   = 51,200,000 (aliases Qn+Kn)
  __bf16* maggH = (__bf16*)(ws + 115200000);    // N*256 bf16  = 25,600,000
  __bf16* maggX = (__bf16*)(ws + 140800000);    // N*96 bf16   =  9,600,000
  float*  sfac  = (float*) (ws + 150400000);    // N f32       =    200,000
  float*  af    = (float*) (ws + 150600000);    // E f32       =    800,000
  int*    ddst  = (int*)   (ws + 151400000);    // E int       =    800,000
  int*    rowptr= (int*)   (ws + 152200000);    // (N+1) int   =    200,064
  int*    wp    = (int*)   (ws + 152400192);    // N int       =    200,000
  int*    bucket= (int*)   (ws + 152600192);    // E int       =    800,000
  float*  cq    = (float*) (ws + 153400192);    // 256 f32
  __bf16* cinw  = (__bf16*)(ws + 153401216);    // 131,072
  __bf16* cwq   = (__bf16*)(ws + 153532288);    // 278,528
  __bf16* cwk   = (__bf16*)(ws + 153810816);    // 344,064
  __bf16* cwv   = (__bf16*)(ws + 154154880);    // 344,064
  __bf16* cow   = (__bf16*)(ws + 154498944);    // 32,768  -> end 154,531,712

  // weight conversions
  k_cvt<<<(65536 + 255) / 256, 256, 0, stream>>>(inw, cinw, 65536);
  k_cvt<<<(139264 + 255) / 256, 256, 0, stream>>>(wq, cwq, 139264);
  k_cvt<<<(172032 + 255) / 256, 256, 0, stream>>>(wk, cwk, 172032);
  k_cvt<<<(172032 + 255) / 256, 256, 0, stream>>>(wvw, cwv, 172032);
  k_cvt<<<(16384 + 255) / 256, 256, 0, stream>>>(ow, cow, 16384);

  k_ddst<<<(EE + 255) / 256, 256, 0, stream>>>(ei, ddst);

  // CSR build (dst is layer-invariant)
  hipMemsetAsync(wp, 0, NN * 4, stream);
  k_hist<<<(EE + 255) / 256, 256, 0, stream>>>(ei, wp);
  k_scan<<<1, 1024, 0, stream>>>(wp, rowptr);
  k_fill<<<(EE + 255) / 256, 256, 0, stream>>>(ei, wp, bucket);

  k_h0<<<(NN + 63) / 64, 256, 0, stream>>>(nf, mem, cinw, inb, hb);

  for (int l = 0; l < 2; ++l) {
    const __bf16* wq_l = cwq + (size_t)l * 256 * 272;
    const __bf16* wk_l = cwk + (size_t)l * 256 * 336;
    const __bf16* wv_l = cwv + (size_t)l * 256 * 336;
    k_aux<<<EE / 4, 256, 0, stream>>>(ef, tim, tew + l * 16, teph + l * 16, aux);
    k_cq<<<1, 256, 0, stream>>>(wq + (size_t)l * 256 * 272, wqb + l * 256, teph + l * 16, cq);
    k_qkn<<<(NN + 63) / 64, 256, 0, stream>>>(hb, wq_l, wk_l, cq, wkb + l * 256, Qn, Kn);
    k_score<<<EE / 64, 256, 0, stream>>>(aux, wk_l, Qn, Kn, ei, ddst, af);
    k_magg<<<NN / 4, 256, 0, stream>>>(hb, aux, ei, rowptr, bucket, af, maggH, maggX, sfac);
    k_vgemm<<<(NN + 63) / 64, 256, 0, stream>>>(maggH, maggX, sfac, wv_l, wvb + l * 256, agg);
    k_norm<<<NN / 4, 256, 0, stream>>>(hb, agg, alw + l * 256, alb + l * 256,
                                       lnw + l * 256, lnb + l * 256);
  }
  k_out<<<(NN + 63) / 64, 256, 0, stream>>>(hb, cow, ob, out);
}

// Round 5
// 1039.265 us; speedup vs baseline: 1.6865x; 1.1246x over previous
//
#include <hip/hip_runtime.h>
#include <hip/hip_bf16.h>
#include <math.h>

#define NN 50000
#define EE 200000

typedef __bf16 bf16x8 __attribute__((ext_vector_type(8)));
typedef __bf16 bf16x4 __attribute__((ext_vector_type(4)));
typedef __bf16 bf16x2 __attribute__((ext_vector_type(2)));
typedef float f32x4 __attribute__((ext_vector_type(4)));

static __device__ __forceinline__ bf16x8 ld8(const __bf16* p) {
  return *reinterpret_cast<const bf16x8*>(p);
}
static __device__ __forceinline__ bf16x4 ld4(const __bf16* p) {
  return *reinterpret_cast<const bf16x4*>(p);
}
static __device__ __forceinline__ bf16x8 cvt8(const float* p) {
  const f32x4* q = reinterpret_cast<const f32x4*>(p);
  f32x4 a = q[0], b = q[1];
  bf16x8 r;
  r[0] = (__bf16)a[0]; r[1] = (__bf16)a[1]; r[2] = (__bf16)a[2]; r[3] = (__bf16)a[3];
  r[4] = (__bf16)b[0]; r[5] = (__bf16)b[1]; r[6] = (__bf16)b[2]; r[7] = (__bf16)b[3];
  return r;
}
static __device__ __forceinline__ bf16x8 zero8() {
  bf16x8 z;
  #pragma unroll
  for (int j = 0; j < 8; ++j) z[j] = (__bf16)0.0f;
  return z;
}

// ---------------- prep kernels ----------------

__global__ __launch_bounds__(256) void k_cvt(const float* __restrict__ src,
                                             __bf16* __restrict__ dst, int n) {
  int i = blockIdx.x * 256 + threadIdx.x;
  if (i < n) dst[i] = (__bf16)src[i];
}

__global__ __launch_bounds__(256) void k_ddst(const int* __restrict__ ei, int* __restrict__ ddst) {
  int e = blockIdx.x * 256 + threadIdx.x;
  if (e < EE) {
    int d = ei[EE + e];
    ddst[e] = ei[EE + d];   // dst[dst[e]]
  }
}

__global__ __launch_bounds__(256) void k_hist(const int* __restrict__ ei, int* __restrict__ cnt) {
  int e = blockIdx.x * 256 + threadIdx.x;
  if (e < EE) atomicAdd(&cnt[ei[EE + e]], 1);
}

__global__ __launch_bounds__(1024) void k_scan(int* __restrict__ wp, int* __restrict__ rowptr) {
  __shared__ int part[1024];
  const int t = threadIdx.x;
  const int CH = 49;                      // 1024*49 = 50176 >= NN
  int lo = t * CH, hi = lo + CH; if (hi > NN) hi = NN; if (lo > NN) lo = NN;
  int s = 0;
  for (int i = lo; i < hi; ++i) s += wp[i];
  part[t] = s;
  __syncthreads();
  for (int off = 1; off < 1024; off <<= 1) {
    int v = (t >= off) ? part[t - off] : 0;
    __syncthreads();
    part[t] += v;
    __syncthreads();
  }
  int run = (t == 0) ? 0 : part[t - 1];
  for (int i = lo; i < hi; ++i) {
    int c = wp[i];
    rowptr[i] = run;
    wp[i] = run;
    run += c;
  }
  if (t == 1023) rowptr[NN] = part[1023];
}

__global__ __launch_bounds__(256) void k_fill(const int* __restrict__ ei,
                                              int* __restrict__ wp,
                                              int* __restrict__ bucket) {
  int e = blockIdx.x * 256 + threadIdx.x;
  if (e < EE) {
    int d = ei[EE + e];
    int pos = atomicAdd(&wp[d], 1);
    bucket[pos] = e;
  }
}

// aux[e] = [edge_feat(64) | tenc(16) | zeros(16)]  (E x 96, bf16)
__global__ __launch_bounds__(256) void k_aux(const float* __restrict__ ef,
                                             const float* __restrict__ tim,
                                             const float* __restrict__ tew,
                                             const float* __restrict__ teph,
                                             __bf16* __restrict__ aux) {
  int lane = threadIdx.x & 63;
  int wv = threadIdx.x >> 6;
  int e = blockIdx.x * 4 + wv;
  float td = -tim[e];
  __bf16* row = aux + (size_t)e * 96;
  row[lane] = (__bf16)ef[(size_t)e * 64 + lane];
  if (lane < 32) {
    if (lane < 16) {
      float wt = td * tew[lane] + teph[lane];
      float v = (lane == 0) ? wt : sinf(wt);
      row[64 + lane] = (__bf16)v;
    } else {
      row[64 + lane] = (__bf16)0.0f;
    }
  }
}

__global__ __launch_bounds__(256) void k_cq(const float* __restrict__ wq_l,
                                            const float* __restrict__ bq_l,
                                            const float* __restrict__ teph_l,
                                            float* __restrict__ cq) {
  int n = threadIdx.x;
  float s = bq_l[n];
  for (int t = 0; t < 16; ++t) {
    float ph = teph_l[t];
    float q = (t == 0) ? ph : sinf(ph);
    s += q * wq_l[(size_t)n * 272 + 256 + t];
  }
  cq[n] = s;
}

// ---------------- h0 = [node_feat|memory] @ in_w^T + in_b  (64x64 wave tiles) ----------------

__global__ __launch_bounds__(256, 3) void k_h0(const float* __restrict__ nf,
                                               const float* __restrict__ mem,
                                               const __bf16* __restrict__ w,
                                               const float* __restrict__ bias,
                                               __bf16* __restrict__ hb) {
  const int lane = threadIdx.x & 63;
  const int wv = threadIdx.x >> 6;
  const int c = lane & 15, g = lane >> 4;
  const int row0 = blockIdx.x * 64;
  const int colbase = wv * 64;

  const float* An[4];
  const float* Am[4];
  const __bf16* Bp[4];
  #pragma unroll
  for (int rt = 0; rt < 4; ++rt) {
    int r = row0 + rt * 16 + c; if (r >= NN) r = NN - 1;
    An[rt] = nf + (size_t)r * 128;
    Am[rt] = mem + (size_t)r * 128;
  }
  #pragma unroll
  for (int ct = 0; ct < 4; ++ct)
    Bp[ct] = w + (size_t)(colbase + ct * 16 + c) * 256;

  f32x4 acc[4][4];
  #pragma unroll
  for (int rt = 0; rt < 4; ++rt)
    for (int ct = 0; ct < 4; ++ct)
      for (int r = 0; r < 4; ++r) acc[rt][ct][r] = 0.0f;

  for (int ks = 0; ks < 8; ++ks) {
    const int k = ks * 32 + g * 8;
    bf16x8 a[4], b[4];
    #pragma unroll
    for (int rt = 0; rt < 4; ++rt)
      a[rt] = cvt8((k < 128) ? (An[rt] + k) : (Am[rt] + (k - 128)));
    #pragma unroll
    for (int ct = 0; ct < 4; ++ct) b[ct] = ld8(Bp[ct] + k);
    #pragma unroll
    for (int rt = 0; rt < 4; ++rt)
      #pragma unroll
      for (int ct = 0; ct < 4; ++ct)
        acc[rt][ct] = __builtin_amdgcn_mfma_f32_16x16x32_bf16(a[rt], b[ct], acc[rt][ct], 0, 0, 0);
  }
  #pragma unroll
  for (int ct = 0; ct < 4; ++ct) {
    const int col = colbase + ct * 16 + c;
    const float bv = bias[col];
    #pragma unroll
    for (int rt = 0; rt < 4; ++rt)
      #pragma unroll
      for (int rr = 0; rr < 4; ++rr) {
        const int row = row0 + rt * 16 + g * 4 + rr;
        if (row < NN) hb[(size_t)row * 256 + col] = (__bf16)(acc[rt][ct][rr] + bv);
      }
  }
}

// ---------------- Qn/Kn GEMMs (two 64x64 passes per wave) ----------------

__global__ __launch_bounds__(256, 3) void k_qkn(const __bf16* __restrict__ hb,
                                                const __bf16* __restrict__ wq_l,
                                                const __bf16* __restrict__ wk_l,
                                                const float* __restrict__ cq,
                                                const float* __restrict__ bk_l,
                                                __bf16* __restrict__ Qn,
                                                __bf16* __restrict__ Kn) {
  const int lane = threadIdx.x & 63;
  const int wv = threadIdx.x >> 6;
  const int c = lane & 15, g = lane >> 4;
  const int row0 = blockIdx.x * 64;
  const int colbase = wv * 64;

  const __bf16* Ar[4];
  #pragma unroll
  for (int rt = 0; rt < 4; ++rt) {
    int r = row0 + rt * 16 + c; if (r >= NN) r = NN - 1;
    Ar[rt] = hb + (size_t)r * 256;
  }

  f32x4 acc[4][4];

  // ---- pass 1: Q ----
  #pragma unroll
  for (int rt = 0; rt < 4; ++rt)
    for (int ct = 0; ct < 4; ++ct)
      for (int r = 0; r < 4; ++r) acc[rt][ct][r] = 0.0f;
  {
    const __bf16* Bp[4];
    #pragma unroll
    for (int ct = 0; ct < 4; ++ct)
      Bp[ct] = wq_l + (size_t)(colbase + ct * 16 + c) * 272;
    for (int ks = 0; ks < 8; ++ks) {
      const int k = ks * 32 + g * 8;
      bf16x8 a[4], b[4];
      #pragma unroll
      for (int rt = 0; rt < 4; ++rt) a[rt] = ld8(Ar[rt] + k);
      #pragma unroll
      for (int ct = 0; ct < 4; ++ct) b[ct] = ld8(Bp[ct] + k);
      #pragma unroll
      for (int rt = 0; rt < 4; ++rt)
        #pragma unroll
        for (int ct = 0; ct < 4; ++ct)
          acc[rt][ct] = __builtin_amdgcn_mfma_f32_16x16x32_bf16(a[rt], b[ct], acc[rt][ct], 0, 0, 0);
    }
  }
  #pragma unroll
  for (int ct = 0; ct < 4; ++ct) {
    const int col = colbase + ct * 16 + c;
    const float cqv = cq[col];
    #pragma unroll
    for (int rt = 0; rt < 4; ++rt)
      #pragma unroll
      for (int rr = 0; rr < 4; ++rr) {
        const int row = row0 + rt * 16 + g * 4 + rr;
        if (row < NN) Qn[(size_t)row * 256 + col] = (__bf16)(acc[rt][ct][rr] + cqv);
      }
  }

  // ---- pass 2: K ----
  #pragma unroll
  for (int rt = 0; rt < 4; ++rt)
    for (int ct = 0; ct < 4; ++ct)
      for (int r = 0; r < 4; ++r) acc[rt][ct][r] = 0.0f;
  {
    const __bf16* Bp[4];
    #pragma unroll
    for (int ct = 0; ct < 4; ++ct)
      Bp[ct] = wk_l + (size_t)(colbase + ct * 16 + c) * 336;
    for (int ks = 0; ks < 8; ++ks) {
      const int k = ks * 32 + g * 8;
      bf16x8 a[4], b[4];
      #pragma unroll
      for (int rt = 0; rt < 4; ++rt) a[rt] = ld8(Ar[rt] + k);
      #pragma unroll
      for (int ct = 0; ct < 4; ++ct) b[ct] = ld8(Bp[ct] + k);
      #pragma unroll
      for (int rt = 0; rt < 4; ++rt)
        #pragma unroll
        for (int ct = 0; ct < 4; ++ct)
          acc[rt][ct] = __builtin_amdgcn_mfma_f32_16x16x32_bf16(a[rt], b[ct], acc[rt][ct], 0, 0, 0);
    }
  }
  #pragma unroll
  for (int ct = 0; ct < 4; ++ct) {
    const int col = colbase + ct * 16 + c;
    const float bkv = bk_l[col];
    #pragma unroll
    for (int rt = 0; rt < 4; ++rt)
      #pragma unroll
      for (int rr = 0; rr < 4; ++rr) {
        const int row = row0 + rt * 16 + g * 4 + rr;
        if (row < NN) Kn[(size_t)row * 256 + col] = (__bf16)(acc[rt][ct][rr] + bkv);
      }
  }
}

// ---------------- fused per-edge scores ----------------

__global__ __launch_bounds__(256, 2) void k_score(const __bf16* __restrict__ aux,
                                                  const __bf16* __restrict__ wk_l,
                                                  const __bf16* __restrict__ Qn,
                                                  const __bf16* __restrict__ Kn,
                                                  const int* __restrict__ ei,
                                                  const int* __restrict__ ddst,
                                                  float* __restrict__ af) {
  const int lane = threadIdx.x & 63;
  const int wv = threadIdx.x >> 6;
  const int c = lane & 15, g = lane >> 4;
  const int row0 = blockIdx.x * 64 + wv * 16;
  const int e = row0 + c;

  f32x4 acc[16];
  #pragma unroll
  for (int t = 0; t < 16; ++t)
    for (int r = 0; r < 4; ++r) acc[t][r] = 0.0f;

  const bf16x8 bz = zero8();
  const __bf16* auxr = aux + (size_t)e * 96;
  for (int ks = 0; ks < 3; ++ks) {
    const int kk = ks * 32 + g * 8;
    bf16x8 b = ld8(auxr + kk);
    #pragma unroll
    for (int t = 0; t < 16; ++t) {
      bf16x8 a = (kk < 80) ? ld8(wk_l + (size_t)(t * 16 + c) * 336 + 256 + kk) : bz;
      acc[t] = __builtin_amdgcn_mfma_f32_16x16x32_bf16(a, b, acc[t], 0, 0, 0);
    }
  }

  const int iq = ddst[e];
  const int is = ei[e];
  const __bf16* Qr = Qn + (size_t)iq * 256;
  const __bf16* Kr = Kn + (size_t)is * 256;

  float sh[4] = {0.0f, 0.0f, 0.0f, 0.0f};
  #pragma unroll
  for (int t = 0; t < 16; ++t) {
    bf16x4 qv = ld4(Qr + t * 16 + g * 4);
    bf16x4 kv = ld4(Kr + t * 16 + g * 4);
    #pragma unroll
    for (int r = 0; r < 4; ++r)
      sh[t >> 2] += (float)qv[r] * ((float)kv[r] + acc[t][r]);
  }
  #pragma unroll
  for (int h = 0; h < 4; ++h) {
    sh[h] += __shfl_xor(sh[h], 16, 64);
    sh[h] += __shfl_xor(sh[h], 32, 64);
  }
  float a0 = 0.0f;
  #pragma unroll
  for (int h = 0; h < 4; ++h) {
    float sc = sh[h] * 0.125f;
    sc = fminf(5.0f, fmaxf(-5.0f, sc));
    a0 += expf(sc);
  }
  if (g == 0) af[e] = a0 * 0.25f;
}

// ---------------- CSR aggregate ----------------

__global__ __launch_bounds__(256, 4) void k_magg(const __bf16* __restrict__ hb,
                                                 const __bf16* __restrict__ aux,
                                                 const int* __restrict__ ei,
                                                 const int* __restrict__ rowptr,
                                                 const int* __restrict__ bucket,
                                                 const float* __restrict__ af,
                                                 __bf16* __restrict__ maggH,
                                                 __bf16* __restrict__ maggX,
                                                 float* __restrict__ sfac) {
  const int lane = threadIdx.x & 63;
  const int wv = threadIdx.x >> 6;
  const int node = blockIdx.x * 4 + wv;
  const int beg = rowptr[node], end = rowptr[node + 1];

  float aH[4] = {0, 0, 0, 0};
  float aX[2] = {0, 0};
  float nrm = 0.0f;
  for (int i = beg; i < end; ++i) {
    const int e = bucket[i];
    const float a = af[e];
    const int s = ei[e];
    bf16x4 hv = ld4(hb + (size_t)s * 256 + lane * 4);
    #pragma unroll
    for (int j = 0; j < 4; ++j) aH[j] += a * (float)hv[j];
    if (lane < 48) {
      bf16x2 xv = *reinterpret_cast<const bf16x2*>(aux + (size_t)e * 96 + lane * 2);
      aX[0] += a * (float)xv[0];
      aX[1] += a * (float)xv[1];
    }
    nrm += a;
  }
  const float inv = 1.0f / (nrm + 1e-8f);
  bf16x4 oh;
  #pragma unroll
  for (int j = 0; j < 4; ++j) oh[j] = (__bf16)(aH[j] * inv);
  *reinterpret_cast<bf16x4*>(maggH + (size_t)node * 256 + lane * 4) = oh;
  if (lane < 48) {
    bf16x2 ox;
    ox[0] = (__bf16)(aX[0] * inv);
    ox[1] = (__bf16)(aX[1] * inv);
    *reinterpret_cast<bf16x2*>(maggX + (size_t)node * 96 + lane * 2) = ox;
  }
  if (lane == 0) sfac[node] = nrm * inv;
}

// ---------------- agg = maggH@WvH^T + maggX@WvX^T + sfac*bv  (64x64 wave tiles) ----------------

__global__ __launch_bounds__(256, 3) void k_vgemm(const __bf16* __restrict__ maggH,
                                                  const __bf16* __restrict__ maggX,
                                                  const float* __restrict__ sfac,
                                                  const __bf16* __restrict__ wv_l,
                                                  const float* __restrict__ bv_l,
                                                  float* __restrict__ agg) {
  const int lane = threadIdx.x & 63;
  const int wv = threadIdx.x >> 6;
  const int c = lane & 15, g = lane >> 4;
  const int row0 = blockIdx.x * 64;
  const int colbase = wv * 64;

  const __bf16* AH[4];
  const __bf16* AX[4];
  const __bf16* Bp[4];
  #pragma unroll
  for (int rt = 0; rt < 4; ++rt) {
    int r = row0 + rt * 16 + c; if (r >= NN) r = NN - 1;
    AH[rt] = maggH + (size_t)r * 256;
    AX[rt] = maggX + (size_t)r * 96;
  }
  #pragma unroll
  for (int ct = 0; ct < 4; ++ct)
    Bp[ct] = wv_l + (size_t)(colbase + ct * 16 + c) * 336;

  f32x4 acc[4][4];
  #pragma unroll
  for (int rt = 0; rt < 4; ++rt)
    for (int ct = 0; ct < 4; ++ct)
      for (int r = 0; r < 4; ++r) acc[rt][ct][r] = 0.0f;

  for (int ks = 0; ks < 8; ++ks) {
    const int k = ks * 32 + g * 8;
    bf16x8 a[4], b[4];
    #pragma unroll
    for (int rt = 0; rt < 4; ++rt) a[rt] = ld8(AH[rt] + k);
    #pragma unroll
    for (int ct = 0; ct < 4; ++ct) b[ct] = ld8(Bp[ct] + k);
    #pragma unroll
    for (int rt = 0; rt < 4; ++rt)
      #pragma unroll
      for (int ct = 0; ct < 4; ++ct)
        acc[rt][ct] = __builtin_amdgcn_mfma_f32_16x16x32_bf16(a[rt], b[ct], acc[rt][ct], 0, 0, 0);
  }
  const bf16x8 bz = zero8();
  for (int ks = 0; ks < 3; ++ks) {
    const int kk = ks * 32 + g * 8;
    bf16x8 a[4], b[4];
    #pragma unroll
    for (int rt = 0; rt < 4; ++rt) a[rt] = ld8(AX[rt] + kk);
    #pragma unroll
    for (int ct = 0; ct < 4; ++ct)
      b[ct] = (kk < 80) ? ld8(Bp[ct] + 256 + kk) : bz;
    #pragma unroll
    for (int rt = 0; rt < 4; ++rt)
      #pragma unroll
      for (int ct = 0; ct < 4; ++ct)
        acc[rt][ct] = __builtin_amdgcn_mfma_f32_16x16x32_bf16(a[rt], b[ct], acc[rt][ct], 0, 0, 0);
  }

  #pragma unroll
  for (int ct = 0; ct < 4; ++ct) {
    const int col = colbase + ct * 16 + c;
    const float bvv = bv_l[col];
    #pragma unroll
    for (int rt = 0; rt < 4; ++rt)
      #pragma unroll
      for (int rr = 0; rr < 4; ++rr) {
        const int row = row0 + rt * 16 + g * 4 + rr;
        if (row < NN) agg[(size_t)row * 256 + col] = acc[rt][ct][rr] + sfac[row] * bvv;
      }
  }
}

// ---------------- per-node double layer-norm ----------------

__global__ __launch_bounds__(256) void k_norm(__bf16* __restrict__ hb,
                                              const float* __restrict__ agg,
                                              const float* __restrict__ aw,
                                              const float* __restrict__ ab,
                                              const float* __restrict__ lw,
                                              const float* __restrict__ lb) {
  const int lane = threadIdx.x & 63;
  const int wv = threadIdx.x >> 6;
  const int node = blockIdx.x * 4 + wv;
  const size_t base = (size_t)node * 256 + lane * 4;
  f32x4 x4 = *reinterpret_cast<const f32x4*>(agg + base);
  float x[4], y[4];
  float s = 0.0f;
  #pragma unroll
  for (int j = 0; j < 4; ++j) { x[j] = x4[j]; s += x[j]; }
  #pragma unroll
  for (int m = 1; m < 64; m <<= 1) s += __shfl_xor(s, m, 64);
  const float mean = s * (1.0f / 256.0f);
  float v = 0.0f;
  #pragma unroll
  for (int j = 0; j < 4; ++j) { float d = x[j] - mean; v += d * d; }
  #pragma unroll
  for (int m = 1; m < 64; m <<= 1) v += __shfl_xor(v, m, 64);
  const float rstd = rsqrtf(v * (1.0f / 256.0f) + 1e-5f);

  bf16x4 hv = *reinterpret_cast<const bf16x4*>(hb + base);
  float s2 = 0.0f;
  #pragma unroll
  for (int j = 0; j < 4; ++j) {
    const int k = lane * 4 + j;
    float hn = (x[j] - mean) * rstd * aw[k] + ab[k];
    y[j] = (float)hv[j] + hn;
    s2 += y[j];
  }
  #pragma unroll
  for (int m = 1; m < 64; m <<= 1) s2 += __shfl_xor(s2, m, 64);
  const float mean2 = s2 * (1.0f / 256.0f);
  float v2 = 0.0f;
  #pragma unroll
  for (int j = 0; j < 4; ++j) { float d = y[j] - mean2; v2 += d * d; }
  #pragma unroll
  for (int m = 1; m < 64; m <<= 1) v2 += __shfl_xor(v2, m, 64);
  const float rstd2 = rsqrtf(v2 * (1.0f / 256.0f) + 1e-5f);
  bf16x4 o;
  #pragma unroll
  for (int j = 0; j < 4; ++j) {
    const int k = lane * 4 + j;
    o[j] = (__bf16)((y[j] - mean2) * rstd2 * lw[k] + lb[k]);
  }
  *reinterpret_cast<bf16x4*>(hb + base) = o;
}

// ---------------- out = gelu(h @ out_w^T + out_b)  (64x64 wave tiles, rows split) ----------------

__global__ __launch_bounds__(256, 3) void k_out(const __bf16* __restrict__ hb,
                                                const __bf16* __restrict__ ow,
                                                const float* __restrict__ ob,
                                                float* __restrict__ out) {
  const int lane = threadIdx.x & 63;
  const int wv = threadIdx.x >> 6;
  const int c = lane & 15, g = lane >> 4;
  const int row0 = blockIdx.x * 256 + wv * 64;

  const __bf16* Ar[4];
  const __bf16* Bp[4];
  #pragma unroll
  for (int rt = 0; rt < 4; ++rt) {
    int r = row0 + rt * 16 + c; if (r >= NN) r = NN - 1;
    Ar[rt] = hb + (size_t)r * 256;
  }
  #pragma unroll
  for (int ct = 0; ct < 4; ++ct)
    Bp[ct] = ow + (size_t)(ct * 16 + c) * 256;

  f32x4 acc[4][4];
  #pragma unroll
  for (int rt = 0; rt < 4; ++rt)
    for (int ct = 0; ct < 4; ++ct)
      for (int r = 0; r < 4; ++r) acc[rt][ct][r] = 0.0f;

  for (int ks = 0; ks < 8; ++ks) {
    const int k = ks * 32 + g * 8;
    bf16x8 a[4], b[4];
    #pragma unroll
    for (int rt = 0; rt < 4; ++rt) a[rt] = ld8(Ar[rt] + k);
    #pragma unroll
    for (int ct = 0; ct < 4; ++ct) b[ct] = ld8(Bp[ct] + k);
    #pragma unroll
    for (int rt = 0; rt < 4; ++rt)
      #pragma unroll
      for (int ct = 0; ct < 4; ++ct)
        acc[rt][ct] = __builtin_amdgcn_mfma_f32_16x16x32_bf16(a[rt], b[ct], acc[rt][ct], 0, 0, 0);
  }
  #pragma unroll
  for (int ct = 0; ct < 4; ++ct) {
    const int col = ct * 16 + c;
    const float bv = ob[col];
    #pragma unroll
    for (int rt = 0; rt < 4; ++rt)
      #pragma unroll
      for (int rr = 0; rr < 4; ++rr) {
        const int row = row0 + rt * 16 + g * 4 + rr;
        if (row < NN) {
          float x = acc[rt][ct][rr] + bv;
          out[(size_t)row * 64 + col] = 0.5f * x * (1.0f + erff(x * 0.70710678118654752f));
        }
      }
  }
}

// ---------------- launcher ----------------

extern "C" void kernel_launch(void* const* d_in, const int* in_sizes, int n_in,
                              void* d_out, int out_size, void* d_ws, size_t ws_size,
                              hipStream_t stream) {
  (void)in_sizes; (void)n_in; (void)out_size; (void)ws_size;
  const float* nf   = (const float*)d_in[0];
  const float* mem  = (const float*)d_in[1];
  const int*   ei   = (const int*)d_in[2];
  const float* ef   = (const float*)d_in[3];
  const float* tim  = (const float*)d_in[4];
  const float* inw  = (const float*)d_in[5];
  const float* inb  = (const float*)d_in[6];
  const float* tew  = (const float*)d_in[7];
  const float* teph = (const float*)d_in[8];
  const float* wq   = (const float*)d_in[9];
  const float* wqb  = (const float*)d_in[10];
  const float* wk   = (const float*)d_in[11];
  const float* wkb  = (const float*)d_in[12];
  const float* wvw  = (const float*)d_in[13];
  const float* wvb  = (const float*)d_in[14];
  const float* alw  = (const float*)d_in[15];
  const float* alb  = (const float*)d_in[16];
  const float* lnw  = (const float*)d_in[17];
  const float* lnb  = (const float*)d_in[18];
  const float* ow   = (const float*)d_in[19];
  const float* ob   = (const float*)d_in[20];
  float* out = (float*)d_out;

  char* ws = (char*)d_ws;
  __bf16* hb    = (__bf16*)(ws + 0);            // N*256 bf16  = 25,600,000
  __bf16* aux   = (__bf16*)(ws + 25600000);     // E*96 bf16   = 38,400,000
  __bf16* Qn    = (__bf16*)(ws + 64000000);     // N*256 bf16  = 25,600,000
  __bf16* Kn    = (__bf16*)(ws + 89600000);     // N*256 bf16  = 25,600,000
  float*  agg   = (float*) (ws + 64000000);     // N*256 f32 (aliases Qn+Kn, disjoint in time)
  __bf16* maggH = (__bf16*)(ws + 115200000);    // N*256 bf16  = 25,600,000
  __bf16* maggX = (__bf16*)(ws + 140800000);    // N*96 bf16   =  9,600,000
  float*  sfac  = (float*) (ws + 150400000);    // N f32
  float*  af    = (float*) (ws + 150600000);    // E f32
  int*    ddst  = (int*)   (ws + 151400000);    // E int
  int*    rowptr= (int*)   (ws + 152200000);    // (N+1) int
  int*    wp    = (int*)   (ws + 152400192);    // N int
  int*    bucket= (int*)   (ws + 152600192);    // E int
  float*  cq    = (float*) (ws + 153400192);    // 256 f32
  __bf16* cinw  = (__bf16*)(ws + 153401216);
  __bf16* cwq   = (__bf16*)(ws + 153532288);
  __bf16* cwk   = (__bf16*)(ws + 153810816);
  __bf16* cwv   = (__bf16*)(ws + 154154880);
  __bf16* cow   = (__bf16*)(ws + 154498944);

  k_cvt<<<(65536 + 255) / 256, 256, 0, stream>>>(inw, cinw, 65536);
  k_cvt<<<(139264 + 255) / 256, 256, 0, stream>>>(wq, cwq, 139264);
  k_cvt<<<(172032 + 255) / 256, 256, 0, stream>>>(wk, cwk, 172032);
  k_cvt<<<(172032 + 255) / 256, 256, 0, stream>>>(wvw, cwv, 172032);
  k_cvt<<<(16384 + 255) / 256, 256, 0, stream>>>(ow, cow, 16384);

  k_ddst<<<(EE + 255) / 256, 256, 0, stream>>>(ei, ddst);

  hipMemsetAsync(wp, 0, NN * 4, stream);
  k_hist<<<(EE + 255) / 256, 256, 0, stream>>>(ei, wp);
  k_scan<<<1, 1024, 0, stream>>>(wp, rowptr);
  k_fill<<<(EE + 255) / 256, 256, 0, stream>>>(ei, wp, bucket);

  k_h0<<<(NN + 63) / 64, 256, 0, stream>>>(nf, mem, cinw, inb, hb);

  for (int l = 0; l < 2; ++l) {
    const __bf16* wq_l = cwq + (size_t)l * 256 * 272;
    const __bf16* wk_l = cwk + (size_t)l * 256 * 336;
    const __bf16* wv_l = cwv + (size_t)l * 256 * 336;
    k_aux<<<EE / 4, 256, 0, stream>>>(ef, tim, tew + l * 16, teph + l * 16, aux);
    k_cq<<<1, 256, 0, stream>>>(wq + (size_t)l * 256 * 272, wqb + l * 256, teph + l * 16, cq);
    k_qkn<<<(NN + 63) / 64, 256, 0, stream>>>(hb, wq_l, wk_l, cq, wkb + l * 256, Qn, Kn);
    k_score<<<EE / 64, 256, 0, stream>>>(aux, wk_l, Qn, Kn, ei, ddst, af);
    k_magg<<<NN / 4, 256, 0, stream>>>(hb, aux, ei, rowptr, bucket, af, maggH, maggX, sfac);
    k_vgemm<<<(NN + 63) / 64, 256, 0, stream>>>(maggH, maggX, sfac, wv_l, wvb + l * 256, agg);
    k_norm<<<NN / 4, 256, 0, stream>>>(hb, agg, alw + l * 256, alb + l * 256,
                                       lnw + l * 256, lnb + l * 256);
  }
  k_out<<<(NN + 255) / 256, 256, 0, stream>>>(hb, cow, ob, out);
}

// Round 6
// 894.181 us; speedup vs baseline: 1.9601x; 1.1623x over previous
//
#include <hip/hip_runtime.h>
#include <hip/hip_bf16.h>
#include <math.h>

#define NN 50000
#define EE 200000

typedef __bf16 bf16x8 __attribute__((ext_vector_type(8)));
typedef __bf16 bf16x4 __attribute__((ext_vector_type(4)));
typedef __bf16 bf16x2 __attribute__((ext_vector_type(2)));
typedef float f32x4 __attribute__((ext_vector_type(4)));

static __device__ __forceinline__ bf16x8 ld8(const __bf16* p) {
  return *reinterpret_cast<const bf16x8*>(p);
}
static __device__ __forceinline__ bf16x4 ld4(const __bf16* p) {
  return *reinterpret_cast<const bf16x4*>(p);
}
static __device__ __forceinline__ bf16x8 cvt8(const float* p) {
  const f32x4* q = reinterpret_cast<const f32x4*>(p);
  f32x4 a = q[0], b = q[1];
  bf16x8 r;
  r[0] = (__bf16)a[0]; r[1] = (__bf16)a[1]; r[2] = (__bf16)a[2]; r[3] = (__bf16)a[3];
  r[4] = (__bf16)b[0]; r[5] = (__bf16)b[1]; r[6] = (__bf16)b[2]; r[7] = (__bf16)b[3];
  return r;
}
static __device__ __forceinline__ bf16x8 zero8() {
  bf16x8 z;
  #pragma unroll
  for (int j = 0; j < 8; ++j) z[j] = (__bf16)0.0f;
  return z;
}

// ---------------- prep kernels ----------------

// fused fp32->bf16 conversion of all 5 weight matrices
__global__ __launch_bounds__(256) void k_cvta(const float* __restrict__ inw,
                                              const float* __restrict__ wq,
                                              const float* __restrict__ wk,
                                              const float* __restrict__ wvw,
                                              const float* __restrict__ ow,
                                              __bf16* __restrict__ cinw,
                                              __bf16* __restrict__ cwq,
                                              __bf16* __restrict__ cwk,
                                              __bf16* __restrict__ cwv,
                                              __bf16* __restrict__ cow) {
  int i = blockIdx.x * 256 + threadIdx.x;
  if (i < 65536) cinw[i] = (__bf16)inw[i];
  else if (i < 204800) { int j = i - 65536;  cwq[j] = (__bf16)wq[j]; }
  else if (i < 376832) { int j = i - 204800; cwk[j] = (__bf16)wk[j]; }
  else if (i < 548864) { int j = i - 376832; cwv[j] = (__bf16)wvw[j]; }
  else if (i < 565248) { int j = i - 548864; cow[j] = (__bf16)ow[j]; }
}

__global__ __launch_bounds__(256) void k_ddst(const int* __restrict__ ei, int* __restrict__ ddst) {
  int e = blockIdx.x * 256 + threadIdx.x;
  if (e < EE) {
    int d = ei[EE + e];
    ddst[e] = ei[EE + d];   // dst[dst[e]]
  }
}

__global__ __launch_bounds__(256) void k_hist(const int* __restrict__ ei, int* __restrict__ cnt) {
  int e = blockIdx.x * 256 + threadIdx.x;
  if (e < EE) atomicAdd(&cnt[ei[EE + e]], 1);
}

// ---- hierarchical exclusive scan of wp (NN counts) -> rowptr, wp ----

__global__ __launch_bounds__(256) void k_blksum(const int* __restrict__ wp, int* __restrict__ bsum) {
  __shared__ int red[256];
  int i = blockIdx.x * 256 + threadIdx.x;
  int v = (i < NN) ? wp[i] : 0;
  red[threadIdx.x] = v;
  __syncthreads();
  for (int off = 128; off > 0; off >>= 1) {
    if (threadIdx.x < off) red[threadIdx.x] += red[threadIdx.x + off];
    __syncthreads();
  }
  if (threadIdx.x == 0) bsum[blockIdx.x] = red[0];
}

__global__ __launch_bounds__(256) void k_scanb(int* __restrict__ bsum, int nb) {
  __shared__ int s[256];
  int t = threadIdx.x;
  int v = (t < nb) ? bsum[t] : 0;
  s[t] = v;
  __syncthreads();
  for (int off = 1; off < 256; off <<= 1) {
    int u = (t >= off) ? s[t - off] : 0;
    __syncthreads();
    s[t] += u;
    __syncthreads();
  }
  if (t < nb) bsum[t] = s[t] - v;   // exclusive block offsets
}

__global__ __launch_bounds__(256) void k_scanc(int* __restrict__ wp,
                                               const int* __restrict__ bsum,
                                               int* __restrict__ rowptr) {
  __shared__ int s[256];
  int i = blockIdx.x * 256 + threadIdx.x;
  int t = threadIdx.x;
  int v = (i < NN) ? wp[i] : 0;
  s[t] = v;
  __syncthreads();
  for (int off = 1; off < 256; off <<= 1) {
    int u = (t >= off) ? s[t - off] : 0;
    __syncthreads();
    s[t] += u;
    __syncthreads();
  }
  int excl = s[t] - v + bsum[blockIdx.x];
  if (i < NN) { rowptr[i] = excl; wp[i] = excl; }
  if (i == 0) rowptr[NN] = EE;
}

__global__ __launch_bounds__(256) void k_fill(const int* __restrict__ ei,
                                              int* __restrict__ wp,
                                              int* __restrict__ bucket) {
  int e = blockIdx.x * 256 + threadIdx.x;
  if (e < EE) {
    int d = ei[EE + e];
    int pos = atomicAdd(&wp[d], 1);
    bucket[pos] = e;
  }
}

// layer-invariant part of aux: [edge_feat(64) | ... | zeros(16)]
__global__ __launch_bounds__(256) void k_auxef(const float* __restrict__ ef,
                                               __bf16* __restrict__ aux) {
  int lane = threadIdx.x & 63;
  int wv = threadIdx.x >> 6;
  int e = blockIdx.x * 4 + wv;
  __bf16* row = aux + (size_t)e * 96;
  row[lane] = (__bf16)ef[(size_t)e * 64 + lane];
  if (lane >= 16 && lane < 32) row[64 + lane] = (__bf16)0.0f;   // offsets 80..95
}

// per-layer tenc strip: aux[e][64..79]
__global__ __launch_bounds__(256) void k_auxte(const float* __restrict__ tim,
                                               const float* __restrict__ tew_l,
                                               const float* __restrict__ teph_l,
                                               __bf16* __restrict__ aux) {
  int idx = blockIdx.x * 256 + threadIdx.x;   // e*16 + t
  int e = idx >> 4, t = idx & 15;
  float td = -tim[e];
  float wt = td * tew_l[t] + teph_l[t];
  float v = (t == 0) ? wt : sinf(wt);
  aux[(size_t)e * 96 + 64 + t] = (__bf16)v;
}

// cq for both layers: cq[l][n] = bq + qte @ wq_aux^T
__global__ __launch_bounds__(256) void k_cq2(const float* __restrict__ wq,
                                             const float* __restrict__ wqb,
                                             const float* __restrict__ teph,
                                             float* __restrict__ cq) {
  int l = blockIdx.x;
  int n = threadIdx.x;
  const float* wq_l = wq + (size_t)l * 256 * 272;
  const float* teph_l = teph + l * 16;
  float s = wqb[l * 256 + n];
  for (int t = 0; t < 16; ++t) {
    float ph = teph_l[t];
    float q = (t == 0) ? ph : sinf(ph);
    s += q * wq_l[(size_t)n * 272 + 256 + t];
  }
  cq[l * 256 + n] = s;
}

// ---------------- h0 = [node_feat|memory] @ in_w^T + in_b  (64x64 wave tiles) ----------------

__global__ __launch_bounds__(256, 3) void k_h0(const float* __restrict__ nf,
                                               const float* __restrict__ mem,
                                               const __bf16* __restrict__ w,
                                               const float* __restrict__ bias,
                                               __bf16* __restrict__ hb) {
  const int lane = threadIdx.x & 63;
  const int wv = threadIdx.x >> 6;
  const int c = lane & 15, g = lane >> 4;
  const int row0 = blockIdx.x * 64;
  const int colbase = wv * 64;

  const float* An[4];
  const float* Am[4];
  const __bf16* Bp[4];
  #pragma unroll
  for (int rt = 0; rt < 4; ++rt) {
    int r = row0 + rt * 16 + c; if (r >= NN) r = NN - 1;
    An[rt] = nf + (size_t)r * 128;
    Am[rt] = mem + (size_t)r * 128;
  }
  #pragma unroll
  for (int ct = 0; ct < 4; ++ct)
    Bp[ct] = w + (size_t)(colbase + ct * 16 + c) * 256;

  f32x4 acc[4][4];
  #pragma unroll
  for (int rt = 0; rt < 4; ++rt)
    for (int ct = 0; ct < 4; ++ct)
      for (int r = 0; r < 4; ++r) acc[rt][ct][r] = 0.0f;

  for (int ks = 0; ks < 8; ++ks) {
    const int k = ks * 32 + g * 8;
    bf16x8 a[4], b[4];
    #pragma unroll
    for (int rt = 0; rt < 4; ++rt)
      a[rt] = cvt8((k < 128) ? (An[rt] + k) : (Am[rt] + (k - 128)));
    #pragma unroll
    for (int ct = 0; ct < 4; ++ct) b[ct] = ld8(Bp[ct] + k);
    #pragma unroll
    for (int rt = 0; rt < 4; ++rt)
      #pragma unroll
      for (int ct = 0; ct < 4; ++ct)
        acc[rt][ct] = __builtin_amdgcn_mfma_f32_16x16x32_bf16(a[rt], b[ct], acc[rt][ct], 0, 0, 0);
  }
  #pragma unroll
  for (int ct = 0; ct < 4; ++ct) {
    const int col = colbase + ct * 16 + c;
    const float bv = bias[col];
    #pragma unroll
    for (int rt = 0; rt < 4; ++rt)
      #pragma unroll
      for (int rr = 0; rr < 4; ++rr) {
        const int row = row0 + rt * 16 + g * 4 + rr;
        if (row < NN) hb[(size_t)row * 256 + col] = (__bf16)(acc[rt][ct][rr] + bv);
      }
  }
}

// ---------------- Qn/Kn GEMMs (two 64x64 passes per wave) ----------------

__global__ __launch_bounds__(256, 3) void k_qkn(const __bf16* __restrict__ hb,
                                                const __bf16* __restrict__ wq_l,
                                                const __bf16* __restrict__ wk_l,
                                                const float* __restrict__ cq,
                                                const float* __restrict__ bk_l,
                                                __bf16* __restrict__ Qn,
                                                __bf16* __restrict__ Kn) {
  const int lane = threadIdx.x & 63;
  const int wv = threadIdx.x >> 6;
  const int c = lane & 15, g = lane >> 4;
  const int row0 = blockIdx.x * 64;
  const int colbase = wv * 64;

  const __bf16* Ar[4];
  #pragma unroll
  for (int rt = 0; rt < 4; ++rt) {
    int r = row0 + rt * 16 + c; if (r >= NN) r = NN - 1;
    Ar[rt] = hb + (size_t)r * 256;
  }

  f32x4 acc[4][4];

  // ---- pass 1: Q ----
  #pragma unroll
  for (int rt = 0; rt < 4; ++rt)
    for (int ct = 0; ct < 4; ++ct)
      for (int r = 0; r < 4; ++r) acc[rt][ct][r] = 0.0f;
  {
    const __bf16* Bp[4];
    #pragma unroll
    for (int ct = 0; ct < 4; ++ct)
      Bp[ct] = wq_l + (size_t)(colbase + ct * 16 + c) * 272;
    for (int ks = 0; ks < 8; ++ks) {
      const int k = ks * 32 + g * 8;
      bf16x8 a[4], b[4];
      #pragma unroll
      for (int rt = 0; rt < 4; ++rt) a[rt] = ld8(Ar[rt] + k);
      #pragma unroll
      for (int ct = 0; ct < 4; ++ct) b[ct] = ld8(Bp[ct] + k);
      #pragma unroll
      for (int rt = 0; rt < 4; ++rt)
        #pragma unroll
        for (int ct = 0; ct < 4; ++ct)
          acc[rt][ct] = __builtin_amdgcn_mfma_f32_16x16x32_bf16(a[rt], b[ct], acc[rt][ct], 0, 0, 0);
    }
  }
  #pragma unroll
  for (int ct = 0; ct < 4; ++ct) {
    const int col = colbase + ct * 16 + c;
    const float cqv = cq[col];
    #pragma unroll
    for (int rt = 0; rt < 4; ++rt)
      #pragma unroll
      for (int rr = 0; rr < 4; ++rr) {
        const int row = row0 + rt * 16 + g * 4 + rr;
        if (row < NN) Qn[(size_t)row * 256 + col] = (__bf16)(acc[rt][ct][rr] + cqv);
      }
  }

  // ---- pass 2: K ----
  #pragma unroll
  for (int rt = 0; rt < 4; ++rt)
    for (int ct = 0; ct < 4; ++ct)
      for (int r = 0; r < 4; ++r) acc[rt][ct][r] = 0.0f;
  {
    const __bf16* Bp[4];
    #pragma unroll
    for (int ct = 0; ct < 4; ++ct)
      Bp[ct] = wk_l + (size_t)(colbase + ct * 16 + c) * 336;
    for (int ks = 0; ks < 8; ++ks) {
      const int k = ks * 32 + g * 8;
      bf16x8 a[4], b[4];
      #pragma unroll
      for (int rt = 0; rt < 4; ++rt) a[rt] = ld8(Ar[rt] + k);
      #pragma unroll
      for (int ct = 0; ct < 4; ++ct) b[ct] = ld8(Bp[ct] + k);
      #pragma unroll
      for (int rt = 0; rt < 4; ++rt)
        #pragma unroll
        for (int ct = 0; ct < 4; ++ct)
          acc[rt][ct] = __builtin_amdgcn_mfma_f32_16x16x32_bf16(a[rt], b[ct], acc[rt][ct], 0, 0, 0);
    }
  }
  #pragma unroll
  for (int ct = 0; ct < 4; ++ct) {
    const int col = colbase + ct * 16 + c;
    const float bkv = bk_l[col];
    #pragma unroll
    for (int rt = 0; rt < 4; ++rt)
      #pragma unroll
      for (int rr = 0; rr < 4; ++rr) {
        const int row = row0 + rt * 16 + g * 4 + rr;
        if (row < NN) Kn[(size_t)row * 256 + col] = (__bf16)(acc[rt][ct][rr] + bkv);
      }
  }
}

// ---------------- fused per-edge scores ----------------

__global__ __launch_bounds__(256, 2) void k_score(const __bf16* __restrict__ aux,
                                                  const __bf16* __restrict__ wk_l,
                                                  const __bf16* __restrict__ Qn,
                                                  const __bf16* __restrict__ Kn,
                                                  const int* __restrict__ ei,
                                                  const int* __restrict__ ddst,
                                                  float* __restrict__ af) {
  const int lane = threadIdx.x & 63;
  const int wv = threadIdx.x >> 6;
  const int c = lane & 15, g = lane >> 4;
  const int row0 = blockIdx.x * 64 + wv * 16;
  const int e = row0 + c;

  f32x4 acc[16];
  #pragma unroll
  for (int t = 0; t < 16; ++t)
    for (int r = 0; r < 4; ++r) acc[t][r] = 0.0f;

  const bf16x8 bz = zero8();
  const __bf16* auxr = aux + (size_t)e * 96;
  for (int ks = 0; ks < 3; ++ks) {
    const int kk = ks * 32 + g * 8;
    bf16x8 b = ld8(auxr + kk);
    #pragma unroll
    for (int t = 0; t < 16; ++t) {
      bf16x8 a = (kk < 80) ? ld8(wk_l + (size_t)(t * 16 + c) * 336 + 256 + kk) : bz;
      acc[t] = __builtin_amdgcn_mfma_f32_16x16x32_bf16(a, b, acc[t], 0, 0, 0);
    }
  }

  const int iq = ddst[e];
  const int is = ei[e];
  const __bf16* Qr = Qn + (size_t)iq * 256;
  const __bf16* Kr = Kn + (size_t)is * 256;

  float sh[4] = {0.0f, 0.0f, 0.0f, 0.0f};
  #pragma unroll
  for (int t = 0; t < 16; ++t) {
    bf16x4 qv = ld4(Qr + t * 16 + g * 4);
    bf16x4 kv = ld4(Kr + t * 16 + g * 4);
    #pragma unroll
    for (int r = 0; r < 4; ++r)
      sh[t >> 2] += (float)qv[r] * ((float)kv[r] + acc[t][r]);
  }
  #pragma unroll
  for (int h = 0; h < 4; ++h) {
    sh[h] += __shfl_xor(sh[h], 16, 64);
    sh[h] += __shfl_xor(sh[h], 32, 64);
  }
  float a0 = 0.0f;
  #pragma unroll
  for (int h = 0; h < 4; ++h) {
    float sc = sh[h] * 0.125f;
    sc = fminf(5.0f, fmaxf(-5.0f, sc));
    a0 += expf(sc);
  }
  if (g == 0) af[e] = a0 * 0.25f;
}

// ---------------- CSR aggregate ----------------

__global__ __launch_bounds__(256, 4) void k_magg(const __bf16* __restrict__ hb,
                                                 const __bf16* __restrict__ aux,
                                                 const int* __restrict__ ei,
                                                 const int* __restrict__ rowptr,
                                                 const int* __restrict__ bucket,
                                                 const float* __restrict__ af,
                                                 __bf16* __restrict__ maggH,
                                                 __bf16* __restrict__ maggX,
                                                 float* __restrict__ sfac) {
  const int lane = threadIdx.x & 63;
  const int wv = threadIdx.x >> 6;
  const int node = blockIdx.x * 4 + wv;
  const int beg = rowptr[node], end = rowptr[node + 1];

  float aH[4] = {0, 0, 0, 0};
  float aX[2] = {0, 0};
  float nrm = 0.0f;
  for (int i = beg; i < end; ++i) {
    const int e = bucket[i];
    const float a = af[e];
    const int s = ei[e];
    bf16x4 hv = ld4(hb + (size_t)s * 256 + lane * 4);
    #pragma unroll
    for (int j = 0; j < 4; ++j) aH[j] += a * (float)hv[j];
    if (lane < 48) {
      bf16x2 xv = *reinterpret_cast<const bf16x2*>(aux + (size_t)e * 96 + lane * 2);
      aX[0] += a * (float)xv[0];
      aX[1] += a * (float)xv[1];
    }
    nrm += a;
  }
  const float inv = 1.0f / (nrm + 1e-8f);
  bf16x4 oh;
  #pragma unroll
  for (int j = 0; j < 4; ++j) oh[j] = (__bf16)(aH[j] * inv);
  *reinterpret_cast<bf16x4*>(maggH + (size_t)node * 256 + lane * 4) = oh;
  if (lane < 48) {
    bf16x2 ox;
    ox[0] = (__bf16)(aX[0] * inv);
    ox[1] = (__bf16)(aX[1] * inv);
    *reinterpret_cast<bf16x2*>(maggX + (size_t)node * 96 + lane * 2) = ox;
  }
  if (lane == 0) sfac[node] = nrm * inv;
}

// ---------------- agg = maggH@WvH^T + maggX@WvX^T + sfac*bv  (64x64 wave tiles) ----------------

__global__ __launch_bounds__(256, 3) void k_vgemm(const __bf16* __restrict__ maggH,
                                                  const __bf16* __restrict__ maggX,
                                                  const float* __restrict__ sfac,
                                                  const __bf16* __restrict__ wv_l,
                                                  const float* __restrict__ bv_l,
                                                  float* __restrict__ agg) {
  const int lane = threadIdx.x & 63;
  const int wv = threadIdx.x >> 6;
  const int c = lane & 15, g = lane >> 4;
  const int row0 = blockIdx.x * 64;
  const int colbase = wv * 64;

  const __bf16* AH[4];
  const __bf16* AX[4];
  const __bf16* Bp[4];
  #pragma unroll
  for (int rt = 0; rt < 4; ++rt) {
    int r = row0 + rt * 16 + c; if (r >= NN) r = NN - 1;
    AH[rt] = maggH + (size_t)r * 256;
    AX[rt] = maggX + (size_t)r * 96;
  }
  #pragma unroll
  for (int ct = 0; ct < 4; ++ct)
    Bp[ct] = wv_l + (size_t)(colbase + ct * 16 + c) * 336;

  f32x4 acc[4][4];
  #pragma unroll
  for (int rt = 0; rt < 4; ++rt)
    for (int ct = 0; ct < 4; ++ct)
      for (int r = 0; r < 4; ++r) acc[rt][ct][r] = 0.0f;

  for (int ks = 0; ks < 8; ++ks) {
    const int k = ks * 32 + g * 8;
    bf16x8 a[4], b[4];
    #pragma unroll
    for (int rt = 0; rt < 4; ++rt) a[rt] = ld8(AH[rt] + k);
    #pragma unroll
    for (int ct = 0; ct < 4; ++ct) b[ct] = ld8(Bp[ct] + k);
    #pragma unroll
    for (int rt = 0; rt < 4; ++rt)
      #pragma unroll
      for (int ct = 0; ct < 4; ++ct)
        acc[rt][ct] = __builtin_amdgcn_mfma_f32_16x16x32_bf16(a[rt], b[ct], acc[rt][ct], 0, 0, 0);
  }
  const bf16x8 bz = zero8();
  for (int ks = 0; ks < 3; ++ks) {
    const int kk = ks * 32 + g * 8;
    bf16x8 a[4], b[4];
    #pragma unroll
    for (int rt = 0; rt < 4; ++rt) a[rt] = ld8(AX[rt] + kk);
    #pragma unroll
    for (int ct = 0; ct < 4; ++ct)
      b[ct] = (kk < 80) ? ld8(Bp[ct] + 256 + kk) : bz;
    #pragma unroll
    for (int rt = 0; rt < 4; ++rt)
      #pragma unroll
      for (int ct = 0; ct < 4; ++ct)
        acc[rt][ct] = __builtin_amdgcn_mfma_f32_16x16x32_bf16(a[rt], b[ct], acc[rt][ct], 0, 0, 0);
  }

  #pragma unroll
  for (int ct = 0; ct < 4; ++ct) {
    const int col = colbase + ct * 16 + c;
    const float bvv = bv_l[col];
    #pragma unroll
    for (int rt = 0; rt < 4; ++rt)
      #pragma unroll
      for (int rr = 0; rr < 4; ++rr) {
        const int row = row0 + rt * 16 + g * 4 + rr;
        if (row < NN) agg[(size_t)row * 256 + col] = acc[rt][ct][rr] + sfac[row] * bvv;
      }
  }
}

// ---------------- per-node double layer-norm ----------------

__global__ __launch_bounds__(256) void k_norm(__bf16* __restrict__ hb,
                                              const float* __restrict__ agg,
                                              const float* __restrict__ aw,
                                              const float* __restrict__ ab,
                                              const float* __restrict__ lw,
                                              const float* __restrict__ lb) {
  const int lane = threadIdx.x & 63;
  const int wv = threadIdx.x >> 6;
  const int node = blockIdx.x * 4 + wv;
  const size_t base = (size_t)node * 256 + lane * 4;
  f32x4 x4 = *reinterpret_cast<const f32x4*>(agg + base);
  float x[4], y[4];
  float s = 0.0f;
  #pragma unroll
  for (int j = 0; j < 4; ++j) { x[j] = x4[j]; s += x[j]; }
  #pragma unroll
  for (int m = 1; m < 64; m <<= 1) s += __shfl_xor(s, m, 64);
  const float mean = s * (1.0f / 256.0f);
  float v = 0.0f;
  #pragma unroll
  for (int j = 0; j < 4; ++j) { float d = x[j] - mean; v += d * d; }
  #pragma unroll
  for (int m = 1; m < 64; m <<= 1) v += __shfl_xor(v, m, 64);
  const float rstd = rsqrtf(v * (1.0f / 256.0f) + 1e-5f);

  bf16x4 hv = *reinterpret_cast<const bf16x4*>(hb + base);
  float s2 = 0.0f;
  #pragma unroll
  for (int j = 0; j < 4; ++j) {
    const int k = lane * 4 + j;
    float hn = (x[j] - mean) * rstd * aw[k] + ab[k];
    y[j] = (float)hv[j] + hn;
    s2 += y[j];
  }
  #pragma unroll
  for (int m = 1; m < 64; m <<= 1) s2 += __shfl_xor(s2, m, 64);
  const float mean2 = s2 * (1.0f / 256.0f);
  float v2 = 0.0f;
  #pragma unroll
  for (int j = 0; j < 4; ++j) { float d = y[j] - mean2; v2 += d * d; }
  #pragma unroll
  for (int m = 1; m < 64; m <<= 1) v2 += __shfl_xor(v2, m, 64);
  const float rstd2 = rsqrtf(v2 * (1.0f / 256.0f) + 1e-5f);
  bf16x4 o;
  #pragma unroll
  for (int j = 0; j < 4; ++j) {
    const int k = lane * 4 + j;
    o[j] = (__bf16)((y[j] - mean2) * rstd2 * lw[k] + lb[k]);
  }
  *reinterpret_cast<bf16x4*>(hb + base) = o;
}

// ---------------- out = gelu(h @ out_w^T + out_b)  (64x64 wave tiles, rows split) ----------------

__global__ __launch_bounds__(256, 3) void k_out(const __bf16* __restrict__ hb,
                                                const __bf16* __restrict__ ow,
                                                const float* __restrict__ ob,
                                                float* __restrict__ out) {
  const int lane = threadIdx.x & 63;
  const int wv = threadIdx.x >> 6;
  const int c = lane & 15, g = lane >> 4;
  const int row0 = blockIdx.x * 256 + wv * 64;

  const __bf16* Ar[4];
  const __bf16* Bp[4];
  #pragma unroll
  for (int rt = 0; rt < 4; ++rt) {
    int r = row0 + rt * 16 + c; if (r >= NN) r = NN - 1;
    Ar[rt] = hb + (size_t)r * 256;
  }
  #pragma unroll
  for (int ct = 0; ct < 4; ++ct)
    Bp[ct] = ow + (size_t)(ct * 16 + c) * 256;

  f32x4 acc[4][4];
  #pragma unroll
  for (int rt = 0; rt < 4; ++rt)
    for (int ct = 0; ct < 4; ++ct)
      for (int r = 0; r < 4; ++r) acc[rt][ct][r] = 0.0f;

  for (int ks = 0; ks < 8; ++ks) {
    const int k = ks * 32 + g * 8;
    bf16x8 a[4], b[4];
    #pragma unroll
    for (int rt = 0; rt < 4; ++rt) a[rt] = ld8(Ar[rt] + k);
    #pragma unroll
    for (int ct = 0; ct < 4; ++ct) b[ct] = ld8(Bp[ct] + k);
    #pragma unroll
    for (int rt = 0; rt < 4; ++rt)
      #pragma unroll
      for (int ct = 0; ct < 4; ++ct)
        acc[rt][ct] = __builtin_amdgcn_mfma_f32_16x16x32_bf16(a[rt], b[ct], acc[rt][ct], 0, 0, 0);
  }
  #pragma unroll
  for (int ct = 0; ct < 4; ++ct) {
    const int col = ct * 16 + c;
    const float bv = ob[col];
    #pragma unroll
    for (int rt = 0; rt < 4; ++rt)
      #pragma unroll
      for (int rr = 0; rr < 4; ++rr) {
        const int row = row0 + rt * 16 + g * 4 + rr;
        if (row < NN) {
          float x = acc[rt][ct][rr] + bv;
          out[(size_t)row * 64 + col] = 0.5f * x * (1.0f + erff(x * 0.70710678118654752f));
        }
      }
  }
}

// ---------------- launcher ----------------

extern "C" void kernel_launch(void* const* d_in, const int* in_sizes, int n_in,
                              void* d_out, int out_size, void* d_ws, size_t ws_size,
                              hipStream_t stream) {
  (void)in_sizes; (void)n_in; (void)out_size; (void)ws_size;
  const float* nf   = (const float*)d_in[0];
  const float* mem  = (const float*)d_in[1];
  const int*   ei   = (const int*)d_in[2];
  const float* ef   = (const float*)d_in[3];
  const float* tim  = (const float*)d_in[4];
  const float* inw  = (const float*)d_in[5];
  const float* inb  = (const float*)d_in[6];
  const float* tew  = (const float*)d_in[7];
  const float* teph = (const float*)d_in[8];
  const float* wq   = (const float*)d_in[9];
  const float* wqb  = (const float*)d_in[10];
  const float* wk   = (const float*)d_in[11];
  const float* wkb  = (const float*)d_in[12];
  const float* wvw  = (const float*)d_in[13];
  const float* wvb  = (const float*)d_in[14];
  const float* alw  = (const float*)d_in[15];
  const float* alb  = (const float*)d_in[16];
  const float* lnw  = (const float*)d_in[17];
  const float* lnb  = (const float*)d_in[18];
  const float* ow   = (const float*)d_in[19];
  const float* ob   = (const float*)d_in[20];
  float* out = (float*)d_out;

  char* ws = (char*)d_ws;
  __bf16* hb    = (__bf16*)(ws + 0);            // N*256 bf16  = 25,600,000
  __bf16* aux   = (__bf16*)(ws + 25600000);     // E*96 bf16   = 38,400,000
  __bf16* Qn    = (__bf16*)(ws + 64000000);     // N*256 bf16  = 25,600,000
  __bf16* Kn    = (__bf16*)(ws + 89600000);     // N*256 bf16  = 25,600,000
  float*  agg   = (float*) (ws + 64000000);     // N*256 f32 (aliases Qn+Kn, disjoint in time)
  __bf16* maggH = (__bf16*)(ws + 115200000);    // N*256 bf16  = 25,600,000
  __bf16* maggX = (__bf16*)(ws + 140800000);    // N*96 bf16   =  9,600,000
  float*  sfac  = (float*) (ws + 150400000);    // N f32
  float*  af    = (float*) (ws + 150600000);    // E f32
  int*    ddst  = (int*)   (ws + 151400000);    // E int
  int*    rowptr= (int*)   (ws + 152200000);    // (N+1) int
  int*    wp    = (int*)   (ws + 152400192);    // N int
  int*    bucket= (int*)   (ws + 152600192);    // E int
  float*  cq    = (float*) (ws + 153400192);    // 2*256 f32 = 2048 B
  int*    bsum  = (int*)   (ws + 153402240);    // 196 int (pad 1024)
  __bf16* cinw  = (__bf16*)(ws + 153403264);    // 131,072
  __bf16* cwq   = (__bf16*)(ws + 153534336);    // 278,528
  __bf16* cwk   = (__bf16*)(ws + 153812864);    // 344,064
  __bf16* cwv   = (__bf16*)(ws + 154156928);    // 344,064
  __bf16* cow   = (__bf16*)(ws + 154500992);    // 32,768 -> end 154,533,760

  k_cvta<<<(565248 + 255) / 256, 256, 0, stream>>>(inw, wq, wk, wvw, ow,
                                                   cinw, cwq, cwk, cwv, cow);
  k_ddst<<<(EE + 255) / 256, 256, 0, stream>>>(ei, ddst);

  // CSR build (hierarchical scan)
  const int NB = (NN + 255) / 256;   // 196
  hipMemsetAsync(wp, 0, NN * 4, stream);
  k_hist<<<(EE + 255) / 256, 256, 0, stream>>>(ei, wp);
  k_blksum<<<NB, 256, 0, stream>>>(wp, bsum);
  k_scanb<<<1, 256, 0, stream>>>(bsum, NB);
  k_scanc<<<NB, 256, 0, stream>>>(wp, bsum, rowptr);
  k_fill<<<(EE + 255) / 256, 256, 0, stream>>>(ei, wp, bucket);

  k_auxef<<<EE / 4, 256, 0, stream>>>(ef, aux);
  k_cq2<<<2, 256, 0, stream>>>(wq, wqb, teph, cq);
  k_h0<<<(NN + 63) / 64, 256, 0, stream>>>(nf, mem, cinw, inb, hb);

  for (int l = 0; l < 2; ++l) {
    const __bf16* wq_l = cwq + (size_t)l * 256 * 272;
    const __bf16* wk_l = cwk + (size_t)l * 256 * 336;
    const __bf16* wv_l = cwv + (size_t)l * 256 * 336;
    k_auxte<<<EE * 16 / 256, 256, 0, stream>>>(tim, tew + l * 16, teph + l * 16, aux);
    k_qkn<<<(NN + 63) / 64, 256, 0, stream>>>(hb, wq_l, wk_l, cq + l * 256, wkb + l * 256, Qn, Kn);
    k_score<<<EE / 64, 256, 0, stream>>>(aux, wk_l, Qn, Kn, ei, ddst, af);
    k_magg<<<NN / 4, 256, 0, stream>>>(hb, aux, ei, rowptr, bucket, af, maggH, maggX, sfac);
    k_vgemm<<<(NN + 63) / 64, 256, 0, stream>>>(maggH, maggX, sfac, wv_l, wvb + l * 256, agg);
    k_norm<<<NN / 4, 256, 0, stream>>>(hb, agg, alw + l * 256, alb + l * 256,
                                       lnw + l * 256, lnb + l * 256);
  }
  k_out<<<(NN + 255) / 256, 256, 0, stream>>>(hb, cow, ob, out);
}

// Round 7
// 876.901 us; speedup vs baseline: 1.9988x; 1.0197x over previous
//
#include <hip/hip_runtime.h>
#include <hip/hip_bf16.h>
#include <math.h>

#define NN 50000
#define EE 200000

typedef __bf16 bf16x8 __attribute__((ext_vector_type(8)));
typedef __bf16 bf16x4 __attribute__((ext_vector_type(4)));
typedef __bf16 bf16x2 __attribute__((ext_vector_type(2)));
typedef float f32x4 __attribute__((ext_vector_type(4)));

static __device__ __forceinline__ bf16x8 ld8(const __bf16* p) {
  return *reinterpret_cast<const bf16x8*>(p);
}
static __device__ __forceinline__ bf16x4 ld4(const __bf16* p) {
  return *reinterpret_cast<const bf16x4*>(p);
}
static __device__ __forceinline__ bf16x8 cvt8(const float* p) {
  const f32x4* q = reinterpret_cast<const f32x4*>(p);
  f32x4 a = q[0], b = q[1];
  bf16x8 r;
  r[0] = (__bf16)a[0]; r[1] = (__bf16)a[1]; r[2] = (__bf16)a[2]; r[3] = (__bf16)a[3];
  r[4] = (__bf16)b[0]; r[5] = (__bf16)b[1]; r[6] = (__bf16)b[2]; r[7] = (__bf16)b[3];
  return r;
}
static __device__ __forceinline__ bf16x8 zero8() {
  bf16x8 z;
  #pragma unroll
  for (int j = 0; j < 8; ++j) z[j] = (__bf16)0.0f;
  return z;
}

// ---------------- prep kernels ----------------

__global__ __launch_bounds__(256) void k_cvta(const float* __restrict__ inw,
                                              const float* __restrict__ wq,
                                              const float* __restrict__ wk,
                                              const float* __restrict__ wvw,
                                              const float* __restrict__ ow,
                                              __bf16* __restrict__ cinw,
                                              __bf16* __restrict__ cwq,
                                              __bf16* __restrict__ cwk,
                                              __bf16* __restrict__ cwv,
                                              __bf16* __restrict__ cow) {
  int i = blockIdx.x * 256 + threadIdx.x;
  if (i < 65536) cinw[i] = (__bf16)inw[i];
  else if (i < 204800) { int j = i - 65536;  cwq[j] = (__bf16)wq[j]; }
  else if (i < 376832) { int j = i - 204800; cwk[j] = (__bf16)wk[j]; }
  else if (i < 548864) { int j = i - 376832; cwv[j] = (__bf16)wvw[j]; }
  else if (i < 565248) { int j = i - 548864; cow[j] = (__bf16)ow[j]; }
}

// transposed K-aux weights: twk[l][h][j][d] = Wk[l][h*64+d][256+j], j<80 (zeros j>=80)
__global__ __launch_bounds__(256) void k_wt(const __bf16* __restrict__ cwk,
                                            __bf16* __restrict__ twk) {
  int i = blockIdx.x * 256 + threadIdx.x;
  if (i >= 49152) return;
  int l = i / 24576, r = i % 24576;
  int h = r / 6144, jd = r % 6144;
  int j = jd / 64, d = jd % 64;
  __bf16 v = (__bf16)0.0f;
  if (j < 80) v = cwk[(size_t)l * 86016 + (size_t)(h * 64 + d) * 336 + 256 + j];
  twk[i] = v;
}

__global__ __launch_bounds__(256) void k_ddst(const int* __restrict__ ei, int* __restrict__ ddst) {
  int e = blockIdx.x * 256 + threadIdx.x;
  if (e < EE) {
    int d = ei[EE + e];
    ddst[e] = ei[EE + d];   // dst[dst[e]]
  }
}

__global__ __launch_bounds__(256) void k_hist(const int* __restrict__ ei, int* __restrict__ cnt) {
  int e = blockIdx.x * 256 + threadIdx.x;
  if (e < EE) atomicAdd(&cnt[ei[EE + e]], 1);
}

__global__ __launch_bounds__(256) void k_blksum(const int* __restrict__ wp, int* __restrict__ bsum) {
  __shared__ int red[256];
  int i = blockIdx.x * 256 + threadIdx.x;
  int v = (i < NN) ? wp[i] : 0;
  red[threadIdx.x] = v;
  __syncthreads();
  for (int off = 128; off > 0; off >>= 1) {
    if (threadIdx.x < off) red[threadIdx.x] += red[threadIdx.x + off];
    __syncthreads();
  }
  if (threadIdx.x == 0) bsum[blockIdx.x] = red[0];
}

__global__ __launch_bounds__(256) void k_scanb(int* __restrict__ bsum, int nb) {
  __shared__ int s[256];
  int t = threadIdx.x;
  int v = (t < nb) ? bsum[t] : 0;
  s[t] = v;
  __syncthreads();
  for (int off = 1; off < 256; off <<= 1) {
    int u = (t >= off) ? s[t - off] : 0;
    __syncthreads();
    s[t] += u;
    __syncthreads();
  }
  if (t < nb) bsum[t] = s[t] - v;
}

__global__ __launch_bounds__(256) void k_scanc(int* __restrict__ wp,
                                               const int* __restrict__ bsum,
                                               int* __restrict__ rowptr) {
  __shared__ int s[256];
  int i = blockIdx.x * 256 + threadIdx.x;
  int t = threadIdx.x;
  int v = (i < NN) ? wp[i] : 0;
  s[t] = v;
  __syncthreads();
  for (int off = 1; off < 256; off <<= 1) {
    int u = (t >= off) ? s[t - off] : 0;
    __syncthreads();
    s[t] += u;
    __syncthreads();
  }
  int excl = s[t] - v + bsum[blockIdx.x];
  if (i < NN) { rowptr[i] = excl; wp[i] = excl; }
  if (i == 0) rowptr[NN] = EE;
}

__global__ __launch_bounds__(256) void k_fill(const int* __restrict__ ei,
                                              int* __restrict__ wp,
                                              int* __restrict__ bucket) {
  int e = blockIdx.x * 256 + threadIdx.x;
  if (e < EE) {
    int d = ei[EE + e];
    int pos = atomicAdd(&wp[d], 1);
    bucket[pos] = e;
  }
}

__global__ __launch_bounds__(256) void k_auxef(const float* __restrict__ ef,
                                               __bf16* __restrict__ aux) {
  int lane = threadIdx.x & 63;
  int wv = threadIdx.x >> 6;
  int e = blockIdx.x * 4 + wv;
  __bf16* row = aux + (size_t)e * 96;
  row[lane] = (__bf16)ef[(size_t)e * 64 + lane];
  if (lane >= 16 && lane < 32) row[64 + lane] = (__bf16)0.0f;   // offsets 80..95
}

__global__ __launch_bounds__(256) void k_auxte(const float* __restrict__ tim,
                                               const float* __restrict__ tew_l,
                                               const float* __restrict__ teph_l,
                                               __bf16* __restrict__ aux) {
  int idx = blockIdx.x * 256 + threadIdx.x;   // e*16 + t
  int e = idx >> 4, t = idx & 15;
  float td = -tim[e];
  float wt = td * tew_l[t] + teph_l[t];
  float v = (t == 0) ? wt : sinf(wt);
  aux[(size_t)e * 96 + 64 + t] = (__bf16)v;
}

__global__ __launch_bounds__(256) void k_cq2(const float* __restrict__ wq,
                                             const float* __restrict__ wqb,
                                             const float* __restrict__ teph,
                                             float* __restrict__ cq) {
  int l = blockIdx.x;
  int n = threadIdx.x;
  const float* wq_l = wq + (size_t)l * 256 * 272;
  const float* teph_l = teph + l * 16;
  float s = wqb[l * 256 + n];
  for (int t = 0; t < 16; ++t) {
    float ph = teph_l[t];
    float q = (t == 0) ? ph : sinf(ph);
    s += q * wq_l[(size_t)n * 272 + 256 + t];
  }
  cq[l * 256 + n] = s;
}

// ---------------- h0 = [node_feat|memory] @ in_w^T + in_b  (64x64 wave tiles) ----------------

__global__ __launch_bounds__(256, 3) void k_h0(const float* __restrict__ nf,
                                               const float* __restrict__ mem,
                                               const __bf16* __restrict__ w,
                                               const float* __restrict__ bias,
                                               __bf16* __restrict__ hb) {
  const int lane = threadIdx.x & 63;
  const int wv = threadIdx.x >> 6;
  const int c = lane & 15, g = lane >> 4;
  const int row0 = blockIdx.x * 64;
  const int colbase = wv * 64;

  const float* An[4];
  const float* Am[4];
  const __bf16* Bp[4];
  #pragma unroll
  for (int rt = 0; rt < 4; ++rt) {
    int r = row0 + rt * 16 + c; if (r >= NN) r = NN - 1;
    An[rt] = nf + (size_t)r * 128;
    Am[rt] = mem + (size_t)r * 128;
  }
  #pragma unroll
  for (int ct = 0; ct < 4; ++ct)
    Bp[ct] = w + (size_t)(colbase + ct * 16 + c) * 256;

  f32x4 acc[4][4];
  #pragma unroll
  for (int rt = 0; rt < 4; ++rt)
    for (int ct = 0; ct < 4; ++ct)
      for (int r = 0; r < 4; ++r) acc[rt][ct][r] = 0.0f;

  for (int ks = 0; ks < 8; ++ks) {
    const int k = ks * 32 + g * 8;
    bf16x8 a[4], b[4];
    #pragma unroll
    for (int rt = 0; rt < 4; ++rt)
      a[rt] = cvt8((k < 128) ? (An[rt] + k) : (Am[rt] + (k - 128)));
    #pragma unroll
    for (int ct = 0; ct < 4; ++ct) b[ct] = ld8(Bp[ct] + k);
    #pragma unroll
    for (int rt = 0; rt < 4; ++rt)
      #pragma unroll
      for (int ct = 0; ct < 4; ++ct)
        acc[rt][ct] = __builtin_amdgcn_mfma_f32_16x16x32_bf16(a[rt], b[ct], acc[rt][ct], 0, 0, 0);
  }
  #pragma unroll
  for (int ct = 0; ct < 4; ++ct) {
    const int col = colbase + ct * 16 + c;
    const float bv = bias[col];
    #pragma unroll
    for (int rt = 0; rt < 4; ++rt)
      #pragma unroll
      for (int rr = 0; rr < 4; ++rr) {
        const int row = row0 + rt * 16 + g * 4 + rr;
        if (row < NN) hb[(size_t)row * 256 + col] = (__bf16)(acc[rt][ct][rr] + bv);
      }
  }
}

// ---------------- Qn/Kn GEMMs (two 64x64 passes per wave) ----------------

__global__ __launch_bounds__(256, 3) void k_qkn(const __bf16* __restrict__ hb,
                                                const __bf16* __restrict__ wq_l,
                                                const __bf16* __restrict__ wk_l,
                                                const float* __restrict__ cq,
                                                const float* __restrict__ bk_l,
                                                __bf16* __restrict__ Qn,
                                                __bf16* __restrict__ Kn) {
  const int lane = threadIdx.x & 63;
  const int wv = threadIdx.x >> 6;
  const int c = lane & 15, g = lane >> 4;
  const int row0 = blockIdx.x * 64;
  const int colbase = wv * 64;

  const __bf16* Ar[4];
  #pragma unroll
  for (int rt = 0; rt < 4; ++rt) {
    int r = row0 + rt * 16 + c; if (r >= NN) r = NN - 1;
    Ar[rt] = hb + (size_t)r * 256;
  }

  f32x4 acc[4][4];

  // ---- pass 1: Q ----
  #pragma unroll
  for (int rt = 0; rt < 4; ++rt)
    for (int ct = 0; ct < 4; ++ct)
      for (int r = 0; r < 4; ++r) acc[rt][ct][r] = 0.0f;
  {
    const __bf16* Bp[4];
    #pragma unroll
    for (int ct = 0; ct < 4; ++ct)
      Bp[ct] = wq_l + (size_t)(colbase + ct * 16 + c) * 272;
    for (int ks = 0; ks < 8; ++ks) {
      const int k = ks * 32 + g * 8;
      bf16x8 a[4], b[4];
      #pragma unroll
      for (int rt = 0; rt < 4; ++rt) a[rt] = ld8(Ar[rt] + k);
      #pragma unroll
      for (int ct = 0; ct < 4; ++ct) b[ct] = ld8(Bp[ct] + k);
      #pragma unroll
      for (int rt = 0; rt < 4; ++rt)
        #pragma unroll
        for (int ct = 0; ct < 4; ++ct)
          acc[rt][ct] = __builtin_amdgcn_mfma_f32_16x16x32_bf16(a[rt], b[ct], acc[rt][ct], 0, 0, 0);
    }
  }
  #pragma unroll
  for (int ct = 0; ct < 4; ++ct) {
    const int col = colbase + ct * 16 + c;
    const float cqv = cq[col];
    #pragma unroll
    for (int rt = 0; rt < 4; ++rt)
      #pragma unroll
      for (int rr = 0; rr < 4; ++rr) {
        const int row = row0 + rt * 16 + g * 4 + rr;
        if (row < NN) Qn[(size_t)row * 256 + col] = (__bf16)(acc[rt][ct][rr] + cqv);
      }
  }

  // ---- pass 2: K ----
  #pragma unroll
  for (int rt = 0; rt < 4; ++rt)
    for (int ct = 0; ct < 4; ++ct)
      for (int r = 0; r < 4; ++r) acc[rt][ct][r] = 0.0f;
  {
    const __bf16* Bp[4];
    #pragma unroll
    for (int ct = 0; ct < 4; ++ct)
      Bp[ct] = wk_l + (size_t)(colbase + ct * 16 + c) * 336;
    for (int ks = 0; ks < 8; ++ks) {
      const int k = ks * 32 + g * 8;
      bf16x8 a[4], b[4];
      #pragma unroll
      for (int rt = 0; rt < 4; ++rt) a[rt] = ld8(Ar[rt] + k);
      #pragma unroll
      for (int ct = 0; ct < 4; ++ct) b[ct] = ld8(Bp[ct] + k);
      #pragma unroll
      for (int rt = 0; rt < 4; ++rt)
        #pragma unroll
        for (int ct = 0; ct < 4; ++ct)
          acc[rt][ct] = __builtin_amdgcn_mfma_f32_16x16x32_bf16(a[rt], b[ct], acc[rt][ct], 0, 0, 0);
    }
  }
  #pragma unroll
  for (int ct = 0; ct < 4; ++ct) {
    const int col = colbase + ct * 16 + c;
    const float bkv = bk_l[col];
    #pragma unroll
    for (int rt = 0; rt < 4; ++rt)
      #pragma unroll
      for (int rr = 0; rr < 4; ++rr) {
        const int row = row0 + rt * 16 + g * 4 + rr;
        if (row < NN) Kn[(size_t)row * 256 + col] = (__bf16)(acc[rt][ct][rr] + bkv);
      }
  }
}

// ---------------- G = per-head Qn @ Wk_aux (N x 4 x 80, row stride 320) ----------------

__global__ __launch_bounds__(256, 3) void k_g(const __bf16* __restrict__ Qn,
                                              const __bf16* __restrict__ twk_l,
                                              __bf16* __restrict__ G) {
  const int lane = threadIdx.x & 63;
  const int h = threadIdx.x >> 6;          // wave = head
  const int c = lane & 15, g = lane >> 4;
  const int row0 = blockIdx.x * 64;

  const __bf16* Ar[4];
  #pragma unroll
  for (int rt = 0; rt < 4; ++rt) {
    int r = row0 + rt * 16 + c; if (r >= NN) r = NN - 1;
    Ar[rt] = Qn + (size_t)r * 256 + h * 64;
  }
  const __bf16* Bp[5];
  #pragma unroll
  for (int ct = 0; ct < 5; ++ct)
    Bp[ct] = twk_l + (size_t)h * 6144 + (size_t)(ct * 16 + c) * 64;

  f32x4 acc[4][5];
  #pragma unroll
  for (int rt = 0; rt < 4; ++rt)
    for (int ct = 0; ct < 5; ++ct)
      for (int r = 0; r < 4; ++r) acc[rt][ct][r] = 0.0f;

  #pragma unroll
  for (int ks = 0; ks < 2; ++ks) {
    const int k = ks * 32 + g * 8;
    bf16x8 a[4], b[5];
    #pragma unroll
    for (int rt = 0; rt < 4; ++rt) a[rt] = ld8(Ar[rt] + k);
    #pragma unroll
    for (int ct = 0; ct < 5; ++ct) b[ct] = ld8(Bp[ct] + k);
    #pragma unroll
    for (int rt = 0; rt < 4; ++rt)
      #pragma unroll
      for (int ct = 0; ct < 5; ++ct)
        acc[rt][ct] = __builtin_amdgcn_mfma_f32_16x16x32_bf16(a[rt], b[ct], acc[rt][ct], 0, 0, 0);
  }
  #pragma unroll
  for (int ct = 0; ct < 5; ++ct) {
    const int j = ct * 16 + c;             // 0..79
    #pragma unroll
    for (int rt = 0; rt < 4; ++rt)
      #pragma unroll
      for (int rr = 0; rr < 4; ++rr) {
        const int row = row0 + rt * 16 + g * 4 + rr;
        if (row < NN) G[(size_t)row * 320 + h * 80 + j] = (__bf16)acc[rt][ct][rr];
      }
  }
}

// ---------------- per-edge scores: af = mean_h exp(clip((Q.K + aux.G)/8)) ----------------

__global__ __launch_bounds__(256, 4) void k_score(const __bf16* __restrict__ aux,
                                                  const __bf16* __restrict__ G,
                                                  const __bf16* __restrict__ Qn,
                                                  const __bf16* __restrict__ Kn,
                                                  const int* __restrict__ ei,
                                                  const int* __restrict__ ddst,
                                                  float* __restrict__ af) {
  const int lane = threadIdx.x & 63;
  const int wv = threadIdx.x >> 6;
  const int c = lane & 15, g = lane >> 4;
  const int e = blockIdx.x * 64 + wv * 16 + c;

  const int iq = ddst[e];
  const int is = ei[e];
  const __bf16* Qr = Qn + (size_t)iq * 256;
  const __bf16* Kr = Kn + (size_t)is * 256;
  const __bf16* Gr = G + (size_t)iq * 320;
  const __bf16* Ax = aux + (size_t)e * 96;

  // aux chunks (zeros at 80..95 make g>=2 of cs=2 contribute 0)
  bf16x8 xs[3];
  #pragma unroll
  for (int cs = 0; cs < 3; ++cs) xs[cs] = ld8(Ax + cs * 32 + g * 8);

  float accH[4] = {0.0f, 0.0f, 0.0f, 0.0f};
  #pragma unroll
  for (int h = 0; h < 4; ++h) {
    #pragma unroll
    for (int ks = 0; ks < 2; ++ks) {
      const int off = h * 64 + ks * 32 + g * 8;
      bf16x8 q = ld8(Qr + off);
      bf16x8 k = ld8(Kr + off);
      #pragma unroll
      for (int j = 0; j < 8; ++j) accH[h] += (float)q[j] * (float)k[j];
    }
    #pragma unroll
    for (int cs = 0; cs < 3; ++cs) {
      bf16x8 gg = ld8(Gr + h * 80 + cs * 32 + g * 8);
      #pragma unroll
      for (int j = 0; j < 8; ++j) accH[h] += (float)xs[cs][j] * (float)gg[j];
    }
  }
  #pragma unroll
  for (int h = 0; h < 4; ++h) {
    accH[h] += __shfl_xor(accH[h], 16, 64);
    accH[h] += __shfl_xor(accH[h], 32, 64);
  }
  if (g == 0) {
    float a0 = 0.0f;
    #pragma unroll
    for (int h = 0; h < 4; ++h) {
      float sc = accH[h] * 0.125f;
      sc = fminf(5.0f, fmaxf(-5.0f, sc));
      a0 += expf(sc);
    }
    af[e] = a0 * 0.25f;
  }
}

// ---------------- CSR aggregate ----------------

__global__ __launch_bounds__(256, 4) void k_magg(const __bf16* __restrict__ hb,
                                                 const __bf16* __restrict__ aux,
                                                 const int* __restrict__ ei,
                                                 const int* __restrict__ rowptr,
                                                 const int* __restrict__ bucket,
                                                 const float* __restrict__ af,
                                                 __bf16* __restrict__ maggH,
                                                 __bf16* __restrict__ maggX,
                                                 float* __restrict__ sfac) {
  const int lane = threadIdx.x & 63;
  const int wv = threadIdx.x >> 6;
  const int node = blockIdx.x * 4 + wv;
  const int beg = rowptr[node], end = rowptr[node + 1];

  float aH[4] = {0, 0, 0, 0};
  float aX[2] = {0, 0};
  float nrm = 0.0f;
  for (int i = beg; i < end; ++i) {
    const int e = bucket[i];
    const float a = af[e];
    const int s = ei[e];
    bf16x4 hv = ld4(hb + (size_t)s * 256 + lane * 4);
    #pragma unroll
    for (int j = 0; j < 4; ++j) aH[j] += a * (float)hv[j];
    if (lane < 48) {
      bf16x2 xv = *reinterpret_cast<const bf16x2*>(aux + (size_t)e * 96 + lane * 2);
      aX[0] += a * (float)xv[0];
      aX[1] += a * (float)xv[1];
    }
    nrm += a;
  }
  const float inv = 1.0f / (nrm + 1e-8f);
  bf16x4 oh;
  #pragma unroll
  for (int j = 0; j < 4; ++j) oh[j] = (__bf16)(aH[j] * inv);
  *reinterpret_cast<bf16x4*>(maggH + (size_t)node * 256 + lane * 4) = oh;
  if (lane < 48) {
    bf16x2 ox;
    ox[0] = (__bf16)(aX[0] * inv);
    ox[1] = (__bf16)(aX[1] * inv);
    *reinterpret_cast<bf16x2*>(maggX + (size_t)node * 96 + lane * 2) = ox;
  }
  if (lane == 0) sfac[node] = nrm * inv;
}

// ---------------- agg = maggH@WvH^T + maggX@WvX^T + sfac*bv  (64x64 wave tiles) ----------------

__global__ __launch_bounds__(256, 3) void k_vgemm(const __bf16* __restrict__ maggH,
                                                  const __bf16* __restrict__ maggX,
                                                  const float* __restrict__ sfac,
                                                  const __bf16* __restrict__ wv_l,
                                                  const float* __restrict__ bv_l,
                                                  float* __restrict__ agg) {
  const int lane = threadIdx.x & 63;
  const int wv = threadIdx.x >> 6;
  const int c = lane & 15, g = lane >> 4;
  const int row0 = blockIdx.x * 64;
  const int colbase = wv * 64;

  const __bf16* AH[4];
  const __bf16* AX[4];
  const __bf16* Bp[4];
  #pragma unroll
  for (int rt = 0; rt < 4; ++rt) {
    int r = row0 + rt * 16 + c; if (r >= NN) r = NN - 1;
    AH[rt] = maggH + (size_t)r * 256;
    AX[rt] = maggX + (size_t)r * 96;
  }
  #pragma unroll
  for (int ct = 0; ct < 4; ++ct)
    Bp[ct] = wv_l + (size_t)(colbase + ct * 16 + c) * 336;

  f32x4 acc[4][4];
  #pragma unroll
  for (int rt = 0; rt < 4; ++rt)
    for (int ct = 0; ct < 4; ++ct)
      for (int r = 0; r < 4; ++r) acc[rt][ct][r] = 0.0f;

  for (int ks = 0; ks < 8; ++ks) {
    const int k = ks * 32 + g * 8;
    bf16x8 a[4], b[4];
    #pragma unroll
    for (int rt = 0; rt < 4; ++rt) a[rt] = ld8(AH[rt] + k);
    #pragma unroll
    for (int ct = 0; ct < 4; ++ct) b[ct] = ld8(Bp[ct] + k);
    #pragma unroll
    for (int rt = 0; rt < 4; ++rt)
      #pragma unroll
      for (int ct = 0; ct < 4; ++ct)
        acc[rt][ct] = __builtin_amdgcn_mfma_f32_16x16x32_bf16(a[rt], b[ct], acc[rt][ct], 0, 0, 0);
  }
  const bf16x8 bz = zero8();
  for (int ks = 0; ks < 3; ++ks) {
    const int kk = ks * 32 + g * 8;
    bf16x8 a[4], b[4];
    #pragma unroll
    for (int rt = 0; rt < 4; ++rt) a[rt] = ld8(AX[rt] + kk);
    #pragma unroll
    for (int ct = 0; ct < 4; ++ct)
      b[ct] = (kk < 80) ? ld8(Bp[ct] + 256 + kk) : bz;
    #pragma unroll
    for (int rt = 0; rt < 4; ++rt)
      #pragma unroll
      for (int ct = 0; ct < 4; ++ct)
        acc[rt][ct] = __builtin_amdgcn_mfma_f32_16x16x32_bf16(a[rt], b[ct], acc[rt][ct], 0, 0, 0);
  }

  #pragma unroll
  for (int ct = 0; ct < 4; ++ct) {
    const int col = colbase + ct * 16 + c;
    const float bvv = bv_l[col];
    #pragma unroll
    for (int rt = 0; rt < 4; ++rt)
      #pragma unroll
      for (int rr = 0; rr < 4; ++rr) {
        const int row = row0 + rt * 16 + g * 4 + rr;
        if (row < NN) agg[(size_t)row * 256 + col] = acc[rt][ct][rr] + sfac[row] * bvv;
      }
  }
}

// ---------------- per-node double layer-norm ----------------

__global__ __launch_bounds__(256) void k_norm(__bf16* __restrict__ hb,
                                              const float* __restrict__ agg,
                                              const float* __restrict__ aw,
                                              const float* __restrict__ ab,
                                              const float* __restrict__ lw,
                                              const float* __restrict__ lb) {
  const int lane = threadIdx.x & 63;
  const int wv = threadIdx.x >> 6;
  const int node = blockIdx.x * 4 + wv;
  const size_t base = (size_t)node * 256 + lane * 4;
  f32x4 x4 = *reinterpret_cast<const f32x4*>(agg + base);
  float x[4], y[4];
  float s = 0.0f;
  #pragma unroll
  for (int j = 0; j < 4; ++j) { x[j] = x4[j]; s += x[j]; }
  #pragma unroll
  for (int m = 1; m < 64; m <<= 1) s += __shfl_xor(s, m, 64);
  const float mean = s * (1.0f / 256.0f);
  float v = 0.0f;
  #pragma unroll
  for (int j = 0; j < 4; ++j) { float d = x[j] - mean; v += d * d; }
  #pragma unroll
  for (int m = 1; m < 64; m <<= 1) v += __shfl_xor(v, m, 64);
  const float rstd = rsqrtf(v * (1.0f / 256.0f) + 1e-5f);

  bf16x4 hv = *reinterpret_cast<const bf16x4*>(hb + base);
  float s2 = 0.0f;
  #pragma unroll
  for (int j = 0; j < 4; ++j) {
    const int k = lane * 4 + j;
    float hn = (x[j] - mean) * rstd * aw[k] + ab[k];
    y[j] = (float)hv[j] + hn;
    s2 += y[j];
  }
  #pragma unroll
  for (int m = 1; m < 64; m <<= 1) s2 += __shfl_xor(s2, m, 64);
  const float mean2 = s2 * (1.0f / 256.0f);
  float v2 = 0.0f;
  #pragma unroll
  for (int j = 0; j < 4; ++j) { float d = y[j] - mean2; v2 += d * d; }
  #pragma unroll
  for (int m = 1; m < 64; m <<= 1) v2 += __shfl_xor(v2, m, 64);
  const float rstd2 = rsqrtf(v2 * (1.0f / 256.0f) + 1e-5f);
  bf16x4 o;
  #pragma unroll
  for (int j = 0; j < 4; ++j) {
    const int k = lane * 4 + j;
    o[j] = (__bf16)((y[j] - mean2) * rstd2 * lw[k] + lb[k]);
  }
  *reinterpret_cast<bf16x4*>(hb + base) = o;
}

// ---------------- out = gelu(h @ out_w^T + out_b)  (64x64 wave tiles, rows split) ----------------

__global__ __launch_bounds__(256, 3) void k_out(const __bf16* __restrict__ hb,
                                                const __bf16* __restrict__ ow,
                                                const float* __restrict__ ob,
                                                float* __restrict__ out) {
  const int lane = threadIdx.x & 63;
  const int wv = threadIdx.x >> 6;
  const int c = lane & 15, g = lane >> 4;
  const int row0 = blockIdx.x * 256 + wv * 64;

  const __bf16* Ar[4];
  const __bf16* Bp[4];
  #pragma unroll
  for (int rt = 0; rt < 4; ++rt) {
    int r = row0 + rt * 16 + c; if (r >= NN) r = NN - 1;
    Ar[rt] = hb + (size_t)r * 256;
  }
  #pragma unroll
  for (int ct = 0; ct < 4; ++ct)
    Bp[ct] = ow + (size_t)(ct * 16 + c) * 256;

  f32x4 acc[4][4];
  #pragma unroll
  for (int rt = 0; rt < 4; ++rt)
    for (int ct = 0; ct < 4; ++ct)
      for (int r = 0; r < 4; ++r) acc[rt][ct][r] = 0.0f;

  for (int ks = 0; ks < 8; ++ks) {
    const int k = ks * 32 + g * 8;
    bf16x8 a[4], b[4];
    #pragma unroll
    for (int rt = 0; rt < 4; ++rt) a[rt] = ld8(Ar[rt] + k);
    #pragma unroll
    for (int ct = 0; ct < 4; ++ct) b[ct] = ld8(Bp[ct] + k);
    #pragma unroll
    for (int rt = 0; rt < 4; ++rt)
      #pragma unroll
      for (int ct = 0; ct < 4; ++ct)
        acc[rt][ct] = __builtin_amdgcn_mfma_f32_16x16x32_bf16(a[rt], b[ct], acc[rt][ct], 0, 0, 0);
  }
  #pragma unroll
  for (int ct = 0; ct < 4; ++ct) {
    const int col = ct * 16 + c;
    const float bv = ob[col];
    #pragma unroll
    for (int rt = 0; rt < 4; ++rt)
      #pragma unroll
      for (int rr = 0; rr < 4; ++rr) {
        const int row = row0 + rt * 16 + g * 4 + rr;
        if (row < NN) {
          float x = acc[rt][ct][rr] + bv;
          out[(size_t)row * 64 + col] = 0.5f * x * (1.0f + erff(x * 0.70710678118654752f));
        }
      }
  }
}

// ---------------- launcher ----------------

extern "C" void kernel_launch(void* const* d_in, const int* in_sizes, int n_in,
                              void* d_out, int out_size, void* d_ws, size_t ws_size,
                              hipStream_t stream) {
  (void)in_sizes; (void)n_in; (void)out_size; (void)ws_size;
  const float* nf   = (const float*)d_in[0];
  const float* mem  = (const float*)d_in[1];
  const int*   ei   = (const int*)d_in[2];
  const float* ef   = (const float*)d_in[3];
  const float* tim  = (const float*)d_in[4];
  const float* inw  = (const float*)d_in[5];
  const float* inb  = (const float*)d_in[6];
  const float* tew  = (const float*)d_in[7];
  const float* teph = (const float*)d_in[8];
  const float* wq   = (const float*)d_in[9];
  const float* wqb  = (const float*)d_in[10];
  const float* wk   = (const float*)d_in[11];
  const float* wkb  = (const float*)d_in[12];
  const float* wvw  = (const float*)d_in[13];
  const float* wvb  = (const float*)d_in[14];
  const float* alw  = (const float*)d_in[15];
  const float* alb  = (const float*)d_in[16];
  const float* lnw  = (const float*)d_in[17];
  const float* lnb  = (const float*)d_in[18];
  const float* ow   = (const float*)d_in[19];
  const float* ob   = (const float*)d_in[20];
  float* out = (float*)d_out;

  char* ws = (char*)d_ws;
  __bf16* hb    = (__bf16*)(ws + 0);            // N*256 bf16  = 25,600,000
  __bf16* aux   = (__bf16*)(ws + 25600000);     // E*96 bf16   = 38,400,000
  __bf16* Qn    = (__bf16*)(ws + 64000000);     // N*256 bf16  = 25,600,000
  __bf16* Kn    = (__bf16*)(ws + 89600000);     // N*256 bf16  = 25,600,000
  float*  agg   = (float*) (ws + 64000000);     // N*256 f32 (aliases Qn+Kn; disjoint in time)
  __bf16* maggH = (__bf16*)(ws + 115200000);    // N*256 bf16  = 25,600,000
  __bf16* maggX = (__bf16*)(ws + 140800000);    // N*96 bf16   =  9,600,000
  __bf16* G     = (__bf16*)(ws + 115200000);    // N*320 bf16 = 32,000,000 (+pad) aliases maggH/X; disjoint in time
  float*  sfac  = (float*) (ws + 150400000);    // N f32
  float*  af    = (float*) (ws + 150600000);    // E f32
  int*    ddst  = (int*)   (ws + 151400000);    // E int
  int*    rowptr= (int*)   (ws + 152200000);    // (N+1) int
  int*    wp    = (int*)   (ws + 152400192);    // N int
  int*    bucket= (int*)   (ws + 152600192);    // E int
  float*  cq    = (float*) (ws + 153400192);    // 2*256 f32
  int*    bsum  = (int*)   (ws + 153402240);    // 196 int
  __bf16* cinw  = (__bf16*)(ws + 153403264);    // 131,072
  __bf16* cwq   = (__bf16*)(ws + 153534336);    // 278,528
  __bf16* cwk   = (__bf16*)(ws + 153812864);    // 344,064
  __bf16* cwv   = (__bf16*)(ws + 154156928);    // 344,064
  __bf16* cow   = (__bf16*)(ws + 154500992);    // 32,768
  __bf16* twk   = (__bf16*)(ws + 154533760);    // 2*4*96*64 bf16 = 98,304 -> end 154,632,064

  k_cvta<<<(565248 + 255) / 256, 256, 0, stream>>>(inw, wq, wk, wvw, ow,
                                                   cinw, cwq, cwk, cwv, cow);
  k_wt<<<(49152 + 255) / 256, 256, 0, stream>>>(cwk, twk);
  k_ddst<<<(EE + 255) / 256, 256, 0, stream>>>(ei, ddst);

  // CSR build (hierarchical scan)
  const int NB = (NN + 255) / 256;   // 196
  hipMemsetAsync(wp, 0, NN * 4, stream);
  k_hist<<<(EE + 255) / 256, 256, 0, stream>>>(ei, wp);
  k_blksum<<<NB, 256, 0, stream>>>(wp, bsum);
  k_scanb<<<1, 256, 0, stream>>>(bsum, NB);
  k_scanc<<<NB, 256, 0, stream>>>(wp, bsum, rowptr);
  k_fill<<<(EE + 255) / 256, 256, 0, stream>>>(ei, wp, bucket);

  k_auxef<<<EE / 4, 256, 0, stream>>>(ef, aux);
  k_cq2<<<2, 256, 0, stream>>>(wq, wqb, teph, cq);
  k_h0<<<(NN + 63) / 64, 256, 0, stream>>>(nf, mem, cinw, inb, hb);

  for (int l = 0; l < 2; ++l) {
    const __bf16* wq_l = cwq + (size_t)l * 256 * 272;
    const __bf16* wk_l = cwk + (size_t)l * 256 * 336;
    const __bf16* wv_l = cwv + (size_t)l * 256 * 336;
    k_auxte<<<EE * 16 / 256, 256, 0, stream>>>(tim, tew + l * 16, teph + l * 16, aux);
    k_qkn<<<(NN + 63) / 64, 256, 0, stream>>>(hb, wq_l, wk_l, cq + l * 256, wkb + l * 256, Qn, Kn);
    k_g<<<(NN + 63) / 64, 256, 0, stream>>>(Qn, twk + (size_t)l * 24576, G);
    k_score<<<EE / 64, 256, 0, stream>>>(aux, G, Qn, Kn, ei, ddst, af);
    k_magg<<<NN / 4, 256, 0, stream>>>(hb, aux, ei, rowptr, bucket, af, maggH, maggX, sfac);
    k_vgemm<<<(NN + 63) / 64, 256, 0, stream>>>(maggH, maggX, sfac, wv_l, wvb + l * 256, agg);
    k_norm<<<NN / 4, 256, 0, stream>>>(hb, agg, alw + l * 256, alb + l * 256,
                                       lnw + l * 256, lnb + l * 256);
  }
  k_out<<<(NN + 255) / 256, 256, 0, stream>>>(hb, cow, ob, out);
}

// Round 8
// 775.264 us; speedup vs baseline: 2.2608x; 1.1311x over previous
//
#include <hip/hip_runtime.h>
#include <hip/hip_bf16.h>
#include <math.h>

#define NN 50000
#define EE 200000

typedef __bf16 bf16x8 __attribute__((ext_vector_type(8)));
typedef __bf16 bf16x4 __attribute__((ext_vector_type(4)));
typedef __bf16 bf16x2 __attribute__((ext_vector_type(2)));
typedef float f32x4 __attribute__((ext_vector_type(4)));

static __device__ __forceinline__ bf16x8 ld8(const __bf16* p) {
  return *reinterpret_cast<const bf16x8*>(p);
}
static __device__ __forceinline__ bf16x4 ld4(const __bf16* p) {
  return *reinterpret_cast<const bf16x4*>(p);
}
static __device__ __forceinline__ bf16x8 cvt8(const float* p) {
  const f32x4* q = reinterpret_cast<const f32x4*>(p);
  f32x4 a = q[0], b = q[1];
  bf16x8 r;
  r[0] = (__bf16)a[0]; r[1] = (__bf16)a[1]; r[2] = (__bf16)a[2]; r[3] = (__bf16)a[3];
  r[4] = (__bf16)b[0]; r[5] = (__bf16)b[1]; r[6] = (__bf16)b[2]; r[7] = (__bf16)b[3];
  return r;
}
static __device__ __forceinline__ bf16x8 zero8() {
  bf16x8 z;
  #pragma unroll
  for (int j = 0; j < 8; ++j) z[j] = (__bf16)0.0f;
  return z;
}

// ---------------- prep kernels ----------------

__global__ __launch_bounds__(256) void k_cvta(const float* __restrict__ inw,
                                              const float* __restrict__ wq,
                                              const float* __restrict__ wk,
                                              const float* __restrict__ wvw,
                                              const float* __restrict__ ow,
                                              __bf16* __restrict__ cinw,
                                              __bf16* __restrict__ cwq,
                                              __bf16* __restrict__ cwk,
                                              __bf16* __restrict__ cwv,
                                              __bf16* __restrict__ cow) {
  int i = blockIdx.x * 256 + threadIdx.x;
  if (i < 65536) cinw[i] = (__bf16)inw[i];
  else if (i < 204800) { int j = i - 65536;  cwq[j] = (__bf16)wq[j]; }
  else if (i < 376832) { int j = i - 204800; cwk[j] = (__bf16)wk[j]; }
  else if (i < 548864) { int j = i - 376832; cwv[j] = (__bf16)wvw[j]; }
  else if (i < 565248) { int j = i - 548864; cow[j] = (__bf16)ow[j]; }
}

// transposed K-aux weights: twk[l][h][j][d] = Wk[l][h*64+d][256+j], j<80 (zeros j>=80)
__global__ __launch_bounds__(256) void k_wt(const __bf16* __restrict__ cwk,
                                            __bf16* __restrict__ twk) {
  int i = blockIdx.x * 256 + threadIdx.x;
  if (i >= 49152) return;
  int l = i / 24576, r = i % 24576;
  int h = r / 6144, jd = r % 6144;
  int j = jd / 64, d = jd % 64;
  __bf16 v = (__bf16)0.0f;
  if (j < 80) v = cwk[(size_t)l * 86016 + (size_t)(h * 64 + d) * 336 + 256 + j];
  twk[i] = v;
}

__global__ __launch_bounds__(256) void k_ddst(const int* __restrict__ ei, int* __restrict__ ddst) {
  int e = blockIdx.x * 256 + threadIdx.x;
  if (e < EE) {
    int d = ei[EE + e];
    ddst[e] = ei[EE + d];   // dst[dst[e]]
  }
}

__global__ __launch_bounds__(256) void k_hist(const int* __restrict__ ei, int* __restrict__ cnt) {
  int e = blockIdx.x * 256 + threadIdx.x;
  if (e < EE) atomicAdd(&cnt[ei[EE + e]], 1);
}

__global__ __launch_bounds__(256) void k_blksum(const int* __restrict__ wp, int* __restrict__ bsum) {
  __shared__ int red[256];
  int i = blockIdx.x * 256 + threadIdx.x;
  int v = (i < NN) ? wp[i] : 0;
  red[threadIdx.x] = v;
  __syncthreads();
  for (int off = 128; off > 0; off >>= 1) {
    if (threadIdx.x < off) red[threadIdx.x] += red[threadIdx.x + off];
    __syncthreads();
  }
  if (threadIdx.x == 0) bsum[blockIdx.x] = red[0];
}

__global__ __launch_bounds__(256) void k_scanb(int* __restrict__ bsum, int nb) {
  __shared__ int s[256];
  int t = threadIdx.x;
  int v = (t < nb) ? bsum[t] : 0;
  s[t] = v;
  __syncthreads();
  for (int off = 1; off < 256; off <<= 1) {
    int u = (t >= off) ? s[t - off] : 0;
    __syncthreads();
    s[t] += u;
    __syncthreads();
  }
  if (t < nb) bsum[t] = s[t] - v;
}

__global__ __launch_bounds__(256) void k_scanc(int* __restrict__ wp,
                                               const int* __restrict__ bsum,
                                               int* __restrict__ rowptr) {
  __shared__ int s[256];
  int i = blockIdx.x * 256 + threadIdx.x;
  int t = threadIdx.x;
  int v = (i < NN) ? wp[i] : 0;
  s[t] = v;
  __syncthreads();
  for (int off = 1; off < 256; off <<= 1) {
    int u = (t >= off) ? s[t - off] : 0;
    __syncthreads();
    s[t] += u;
    __syncthreads();
  }
  int excl = s[t] - v + bsum[blockIdx.x];
  if (i < NN) { rowptr[i] = excl; wp[i] = excl; }
  if (i == 0) rowptr[NN] = EE;
}

__global__ __launch_bounds__(256) void k_fill(const int* __restrict__ ei,
                                              int* __restrict__ wp,
                                              int* __restrict__ bucket) {
  int e = blockIdx.x * 256 + threadIdx.x;
  if (e < EE) {
    int d = ei[EE + e];
    int pos = atomicAdd(&wp[d], 1);
    bucket[pos] = e;
  }
}

__global__ __launch_bounds__(256) void k_auxef(const float* __restrict__ ef,
                                               __bf16* __restrict__ aux) {
  int lane = threadIdx.x & 63;
  int wv = threadIdx.x >> 6;
  int e = blockIdx.x * 4 + wv;
  __bf16* row = aux + (size_t)e * 96;
  row[lane] = (__bf16)ef[(size_t)e * 64 + lane];
  if (lane >= 16 && lane < 32) row[64 + lane] = (__bf16)0.0f;   // offsets 80..95
}

__global__ __launch_bounds__(256) void k_auxte(const float* __restrict__ tim,
                                               const float* __restrict__ tew_l,
                                               const float* __restrict__ teph_l,
                                               __bf16* __restrict__ aux) {
  int idx = blockIdx.x * 256 + threadIdx.x;   // e*16 + t
  int e = idx >> 4, t = idx & 15;
  float td = -tim[e];
  float wt = td * tew_l[t] + teph_l[t];
  float v = (t == 0) ? wt : sinf(wt);
  aux[(size_t)e * 96 + 64 + t] = (__bf16)v;
}

__global__ __launch_bounds__(256) void k_cq2(const float* __restrict__ wq,
                                             const float* __restrict__ wqb,
                                             const float* __restrict__ teph,
                                             float* __restrict__ cq) {
  int l = blockIdx.x;
  int n = threadIdx.x;
  const float* wq_l = wq + (size_t)l * 256 * 272;
  const float* teph_l = teph + l * 16;
  float s = wqb[l * 256 + n];
  for (int t = 0; t < 16; ++t) {
    float ph = teph_l[t];
    float q = (t == 0) ? ph : sinf(ph);
    s += q * wq_l[(size_t)n * 272 + 256 + t];
  }
  cq[l * 256 + n] = s;
}

// ---- LDS-transpose store helper: tile[64][68] per wave, coalesced 128B rows ----
// write phase: tile[r][col] = val (MFMA layout); read phase: 8 iters, 8 lanes/row.

// ---------------- h0 = [node_feat|memory] @ in_w^T + in_b  (64x64 wave tiles) ----------------

__global__ __launch_bounds__(256, 3) void k_h0(const float* __restrict__ nf,
                                               const float* __restrict__ mem,
                                               const __bf16* __restrict__ w,
                                               const float* __restrict__ bias,
                                               __bf16* __restrict__ hb) {
  __shared__ __bf16 tile[4][64][68];
  const int lane = threadIdx.x & 63;
  const int wv = threadIdx.x >> 6;
  const int c = lane & 15, g = lane >> 4;
  const int row0 = blockIdx.x * 64;
  const int colbase = wv * 64;

  const float* An[4];
  const float* Am[4];
  const __bf16* Bp[4];
  #pragma unroll
  for (int rt = 0; rt < 4; ++rt) {
    int r = row0 + rt * 16 + c; if (r >= NN) r = NN - 1;
    An[rt] = nf + (size_t)r * 128;
    Am[rt] = mem + (size_t)r * 128;
  }
  #pragma unroll
  for (int ct = 0; ct < 4; ++ct)
    Bp[ct] = w + (size_t)(colbase + ct * 16 + c) * 256;

  f32x4 acc[4][4];
  #pragma unroll
  for (int rt = 0; rt < 4; ++rt)
    for (int ct = 0; ct < 4; ++ct)
      for (int r = 0; r < 4; ++r) acc[rt][ct][r] = 0.0f;

  for (int ks = 0; ks < 8; ++ks) {
    const int k = ks * 32 + g * 8;
    bf16x8 a[4], b[4];
    #pragma unroll
    for (int rt = 0; rt < 4; ++rt)
      a[rt] = cvt8((k < 128) ? (An[rt] + k) : (Am[rt] + (k - 128)));
    #pragma unroll
    for (int ct = 0; ct < 4; ++ct) b[ct] = ld8(Bp[ct] + k);
    #pragma unroll
    for (int rt = 0; rt < 4; ++rt)
      #pragma unroll
      for (int ct = 0; ct < 4; ++ct)
        acc[rt][ct] = __builtin_amdgcn_mfma_f32_16x16x32_bf16(a[rt], b[ct], acc[rt][ct], 0, 0, 0);
  }
  #pragma unroll
  for (int ct = 0; ct < 4; ++ct) {
    const float bv = bias[colbase + ct * 16 + c];
    #pragma unroll
    for (int rt = 0; rt < 4; ++rt)
      #pragma unroll
      for (int rr = 0; rr < 4; ++rr)
        tile[wv][rt * 16 + g * 4 + rr][ct * 16 + c] = (__bf16)(acc[rt][ct][rr] + bv);
  }
  #pragma unroll
  for (int i = 0; i < 8; ++i) {
    const int r = i * 8 + (lane >> 3);
    const int ck = lane & 7;
    bf16x8 v = *reinterpret_cast<const bf16x8*>(&tile[wv][r][ck * 8]);
    const int row = row0 + r;
    if (row < NN)
      *reinterpret_cast<bf16x8*>(hb + (size_t)row * 256 + colbase + ck * 8) = v;
  }
}

// ---------------- Qn/Kn GEMMs (two 64x64 passes per wave, LDS store epilogue) ----------------

__global__ __launch_bounds__(256, 3) void k_qkn(const __bf16* __restrict__ hb,
                                                const __bf16* __restrict__ wq_l,
                                                const __bf16* __restrict__ wk_l,
                                                const float* __restrict__ cq,
                                                const float* __restrict__ bk_l,
                                                __bf16* __restrict__ Qn,
                                                __bf16* __restrict__ Kn) {
  __shared__ __bf16 tile[4][64][68];
  const int lane = threadIdx.x & 63;
  const int wv = threadIdx.x >> 6;
  const int c = lane & 15, g = lane >> 4;
  const int row0 = blockIdx.x * 64;
  const int colbase = wv * 64;

  const __bf16* Ar[4];
  #pragma unroll
  for (int rt = 0; rt < 4; ++rt) {
    int r = row0 + rt * 16 + c; if (r >= NN) r = NN - 1;
    Ar[rt] = hb + (size_t)r * 256;
  }

  f32x4 acc[4][4];

  // ---- pass 1: Q ----
  #pragma unroll
  for (int rt = 0; rt < 4; ++rt)
    for (int ct = 0; ct < 4; ++ct)
      for (int r = 0; r < 4; ++r) acc[rt][ct][r] = 0.0f;
  {
    const __bf16* Bp[4];
    #pragma unroll
    for (int ct = 0; ct < 4; ++ct)
      Bp[ct] = wq_l + (size_t)(colbase + ct * 16 + c) * 272;
    for (int ks = 0; ks < 8; ++ks) {
      const int k = ks * 32 + g * 8;
      bf16x8 a[4], b[4];
      #pragma unroll
      for (int rt = 0; rt < 4; ++rt) a[rt] = ld8(Ar[rt] + k);
      #pragma unroll
      for (int ct = 0; ct < 4; ++ct) b[ct] = ld8(Bp[ct] + k);
      #pragma unroll
      for (int rt = 0; rt < 4; ++rt)
        #pragma unroll
        for (int ct = 0; ct < 4; ++ct)
          acc[rt][ct] = __builtin_amdgcn_mfma_f32_16x16x32_bf16(a[rt], b[ct], acc[rt][ct], 0, 0, 0);
    }
  }
  #pragma unroll
  for (int ct = 0; ct < 4; ++ct) {
    const float cqv = cq[colbase + ct * 16 + c];
    #pragma unroll
    for (int rt = 0; rt < 4; ++rt)
      #pragma unroll
      for (int rr = 0; rr < 4; ++rr)
        tile[wv][rt * 16 + g * 4 + rr][ct * 16 + c] = (__bf16)(acc[rt][ct][rr] + cqv);
  }
  #pragma unroll
  for (int i = 0; i < 8; ++i) {
    const int r = i * 8 + (lane >> 3);
    const int ck = lane & 7;
    bf16x8 v = *reinterpret_cast<const bf16x8*>(&tile[wv][r][ck * 8]);
    const int row = row0 + r;
    if (row < NN)
      *reinterpret_cast<bf16x8*>(Qn + (size_t)row * 256 + colbase + ck * 8) = v;
  }

  // ---- pass 2: K ----
  #pragma unroll
  for (int rt = 0; rt < 4; ++rt)
    for (int ct = 0; ct < 4; ++ct)
      for (int r = 0; r < 4; ++r) acc[rt][ct][r] = 0.0f;
  {
    const __bf16* Bp[4];
    #pragma unroll
    for (int ct = 0; ct < 4; ++ct)
      Bp[ct] = wk_l + (size_t)(colbase + ct * 16 + c) * 336;
    for (int ks = 0; ks < 8; ++ks) {
      const int k = ks * 32 + g * 8;
      bf16x8 a[4], b[4];
      #pragma unroll
      for (int rt = 0; rt < 4; ++rt) a[rt] = ld8(Ar[rt] + k);
      #pragma unroll
      for (int ct = 0; ct < 4; ++ct) b[ct] = ld8(Bp[ct] + k);
      #pragma unroll
      for (int rt = 0; rt < 4; ++rt)
        #pragma unroll
        for (int ct = 0; ct < 4; ++ct)
          acc[rt][ct] = __builtin_amdgcn_mfma_f32_16x16x32_bf16(a[rt], b[ct], acc[rt][ct], 0, 0, 0);
    }
  }
  #pragma unroll
  for (int ct = 0; ct < 4; ++ct) {
    const float bkv = bk_l[colbase + ct * 16 + c];
    #pragma unroll
    for (int rt = 0; rt < 4; ++rt)
      #pragma unroll
      for (int rr = 0; rr < 4; ++rr)
        tile[wv][rt * 16 + g * 4 + rr][ct * 16 + c] = (__bf16)(acc[rt][ct][rr] + bkv);
  }
  #pragma unroll
  for (int i = 0; i < 8; ++i) {
    const int r = i * 8 + (lane >> 3);
    const int ck = lane & 7;
    bf16x8 v = *reinterpret_cast<const bf16x8*>(&tile[wv][r][ck * 8]);
    const int row = row0 + r;
    if (row < NN)
      *reinterpret_cast<bf16x8*>(Kn + (size_t)row * 256 + colbase + ck * 8) = v;
  }
}

// ---------------- G = per-head Qn @ Wk_aux (N x 4 x 80), LDS store epilogue ----------------

__global__ __launch_bounds__(256, 3) void k_g(const __bf16* __restrict__ Qn,
                                              const __bf16* __restrict__ twk_l,
                                              __bf16* __restrict__ G) {
  __shared__ __bf16 tile[4][64][84];
  const int lane = threadIdx.x & 63;
  const int h = threadIdx.x >> 6;          // wave = head
  const int c = lane & 15, g = lane >> 4;
  const int row0 = blockIdx.x * 64;

  const __bf16* Ar[4];
  #pragma unroll
  for (int rt = 0; rt < 4; ++rt) {
    int r = row0 + rt * 16 + c; if (r >= NN) r = NN - 1;
    Ar[rt] = Qn + (size_t)r * 256 + h * 64;
  }
  const __bf16* Bp[5];
  #pragma unroll
  for (int ct = 0; ct < 5; ++ct)
    Bp[ct] = twk_l + (size_t)h * 6144 + (size_t)(ct * 16 + c) * 64;

  f32x4 acc[4][5];
  #pragma unroll
  for (int rt = 0; rt < 4; ++rt)
    for (int ct = 0; ct < 5; ++ct)
      for (int r = 0; r < 4; ++r) acc[rt][ct][r] = 0.0f;

  #pragma unroll
  for (int ks = 0; ks < 2; ++ks) {
    const int k = ks * 32 + g * 8;
    bf16x8 a[4], b[5];
    #pragma unroll
    for (int rt = 0; rt < 4; ++rt) a[rt] = ld8(Ar[rt] + k);
    #pragma unroll
    for (int ct = 0; ct < 5; ++ct) b[ct] = ld8(Bp[ct] + k);
    #pragma unroll
    for (int rt = 0; rt < 4; ++rt)
      #pragma unroll
      for (int ct = 0; ct < 5; ++ct)
        acc[rt][ct] = __builtin_amdgcn_mfma_f32_16x16x32_bf16(a[rt], b[ct], acc[rt][ct], 0, 0, 0);
  }
  #pragma unroll
  for (int ct = 0; ct < 5; ++ct) {
    #pragma unroll
    for (int rt = 0; rt < 4; ++rt)
      #pragma unroll
      for (int rr = 0; rr < 4; ++rr)
        tile[h][rt * 16 + g * 4 + rr][ct * 16 + c] = (__bf16)acc[rt][ct][rr];
  }
  // write out: 64 rows x 160B strip; 10 iters x 64 lanes x 16B
  #pragma unroll
  for (int i = 0; i < 10; ++i) {
    const int idx = i * 64 + lane;   // < 640
    const int r = idx / 10;
    const int ck = idx % 10;
    bf16x8 v = *reinterpret_cast<const bf16x8*>(&tile[h][r][ck * 8]);
    const int row = row0 + r;
    if (row < NN)
      *reinterpret_cast<bf16x8*>(G + (size_t)row * 320 + h * 80 + ck * 8) = v;
  }
}

// ---------------- per-edge scores: af = mean_h exp(clip((Q.K + aux.G)/8)) ----------------

__global__ __launch_bounds__(256, 4) void k_score(const __bf16* __restrict__ aux,
                                                  const __bf16* __restrict__ G,
                                                  const __bf16* __restrict__ Qn,
                                                  const __bf16* __restrict__ Kn,
                                                  const int* __restrict__ ei,
                                                  const int* __restrict__ ddst,
                                                  float* __restrict__ af) {
  const int lane = threadIdx.x & 63;
  const int wv = threadIdx.x >> 6;
  const int c = lane & 15, g = lane >> 4;
  const int e = blockIdx.x * 64 + wv * 16 + c;

  const int iq = ddst[e];
  const int is = ei[e];
  const __bf16* Qr = Qn + (size_t)iq * 256;
  const __bf16* Kr = Kn + (size_t)is * 256;
  const __bf16* Gr = G + (size_t)iq * 320;
  const __bf16* Ax = aux + (size_t)e * 96;

  bf16x8 xs[3];
  #pragma unroll
  for (int cs = 0; cs < 3; ++cs) xs[cs] = ld8(Ax + cs * 32 + g * 8);

  float accH[4] = {0.0f, 0.0f, 0.0f, 0.0f};
  #pragma unroll
  for (int h = 0; h < 4; ++h) {
    #pragma unroll
    for (int ks = 0; ks < 2; ++ks) {
      const int off = h * 64 + ks * 32 + g * 8;
      bf16x8 q = ld8(Qr + off);
      bf16x8 k = ld8(Kr + off);
      #pragma unroll
      for (int j = 0; j < 8; ++j) accH[h] += (float)q[j] * (float)k[j];
    }
    #pragma unroll
    for (int cs = 0; cs < 3; ++cs) {
      bf16x8 gg = ld8(Gr + h * 80 + cs * 32 + g * 8);
      #pragma unroll
      for (int j = 0; j < 8; ++j) accH[h] += (float)xs[cs][j] * (float)gg[j];
    }
  }
  #pragma unroll
  for (int h = 0; h < 4; ++h) {
    accH[h] += __shfl_xor(accH[h], 16, 64);
    accH[h] += __shfl_xor(accH[h], 32, 64);
  }
  if (g == 0) {
    float a0 = 0.0f;
    #pragma unroll
    for (int h = 0; h < 4; ++h) {
      float sc = accH[h] * 0.125f;
      sc = fminf(5.0f, fmaxf(-5.0f, sc));
      a0 += expf(sc);
    }
    af[e] = a0 * 0.25f;
  }
}

// ---------------- CSR aggregate ----------------

__global__ __launch_bounds__(256, 4) void k_magg(const __bf16* __restrict__ hb,
                                                 const __bf16* __restrict__ aux,
                                                 const int* __restrict__ ei,
                                                 const int* __restrict__ rowptr,
                                                 const int* __restrict__ bucket,
                                                 const float* __restrict__ af,
                                                 __bf16* __restrict__ maggH,
                                                 __bf16* __restrict__ maggX,
                                                 float* __restrict__ sfac) {
  const int lane = threadIdx.x & 63;
  const int wv = threadIdx.x >> 6;
  const int node = blockIdx.x * 4 + wv;
  const int beg = rowptr[node], end = rowptr[node + 1];

  float aH[4] = {0, 0, 0, 0};
  float aX[2] = {0, 0};
  float nrm = 0.0f;
  for (int i = beg; i < end; ++i) {
    const int e = bucket[i];
    const float a = af[e];
    const int s = ei[e];
    bf16x4 hv = ld4(hb + (size_t)s * 256 + lane * 4);
    #pragma unroll
    for (int j = 0; j < 4; ++j) aH[j] += a * (float)hv[j];
    if (lane < 48) {
      bf16x2 xv = *reinterpret_cast<const bf16x2*>(aux + (size_t)e * 96 + lane * 2);
      aX[0] += a * (float)xv[0];
      aX[1] += a * (float)xv[1];
    }
    nrm += a;
  }
  const float inv = 1.0f / (nrm + 1e-8f);
  bf16x4 oh;
  #pragma unroll
  for (int j = 0; j < 4; ++j) oh[j] = (__bf16)(aH[j] * inv);
  *reinterpret_cast<bf16x4*>(maggH + (size_t)node * 256 + lane * 4) = oh;
  if (lane < 48) {
    bf16x2 ox;
    ox[0] = (__bf16)(aX[0] * inv);
    ox[1] = (__bf16)(aX[1] * inv);
    *reinterpret_cast<bf16x2*>(maggX + (size_t)node * 96 + lane * 2) = ox;
  }
  if (lane == 0) sfac[node] = nrm * inv;
}

// ---------------- agg = maggH@WvH^T + maggX@WvX^T + sfac*bv  (64x64 wave tiles) ----------------

__global__ __launch_bounds__(256, 3) void k_vgemm(const __bf16* __restrict__ maggH,
                                                  const __bf16* __restrict__ maggX,
                                                  const float* __restrict__ sfac,
                                                  const __bf16* __restrict__ wv_l,
                                                  const float* __restrict__ bv_l,
                                                  float* __restrict__ agg) {
  const int lane = threadIdx.x & 63;
  const int wv = threadIdx.x >> 6;
  const int c = lane & 15, g = lane >> 4;
  const int row0 = blockIdx.x * 64;
  const int colbase = wv * 64;

  const __bf16* AH[4];
  const __bf16* AX[4];
  const __bf16* Bp[4];
  #pragma unroll
  for (int rt = 0; rt < 4; ++rt) {
    int r = row0 + rt * 16 + c; if (r >= NN) r = NN - 1;
    AH[rt] = maggH + (size_t)r * 256;
    AX[rt] = maggX + (size_t)r * 96;
  }
  #pragma unroll
  for (int ct = 0; ct < 4; ++ct)
    Bp[ct] = wv_l + (size_t)(colbase + ct * 16 + c) * 336;

  f32x4 acc[4][4];
  #pragma unroll
  for (int rt = 0; rt < 4; ++rt)
    for (int ct = 0; ct < 4; ++ct)
      for (int r = 0; r < 4; ++r) acc[rt][ct][r] = 0.0f;

  for (int ks = 0; ks < 8; ++ks) {
    const int k = ks * 32 + g * 8;
    bf16x8 a[4], b[4];
    #pragma unroll
    for (int rt = 0; rt < 4; ++rt) a[rt] = ld8(AH[rt] + k);
    #pragma unroll
    for (int ct = 0; ct < 4; ++ct) b[ct] = ld8(Bp[ct] + k);
    #pragma unroll
    for (int rt = 0; rt < 4; ++rt)
      #pragma unroll
      for (int ct = 0; ct < 4; ++ct)
        acc[rt][ct] = __builtin_amdgcn_mfma_f32_16x16x32_bf16(a[rt], b[ct], acc[rt][ct], 0, 0, 0);
  }
  const bf16x8 bz = zero8();
  for (int ks = 0; ks < 3; ++ks) {
    const int kk = ks * 32 + g * 8;
    bf16x8 a[4], b[4];
    #pragma unroll
    for (int rt = 0; rt < 4; ++rt) a[rt] = ld8(AX[rt] + kk);
    #pragma unroll
    for (int ct = 0; ct < 4; ++ct)
      b[ct] = (kk < 80) ? ld8(Bp[ct] + 256 + kk) : bz;
    #pragma unroll
    for (int rt = 0; rt < 4; ++rt)
      #pragma unroll
      for (int ct = 0; ct < 4; ++ct)
        acc[rt][ct] = __builtin_amdgcn_mfma_f32_16x16x32_bf16(a[rt], b[ct], acc[rt][ct], 0, 0, 0);
  }

  #pragma unroll
  for (int ct = 0; ct < 4; ++ct) {
    const int col = colbase + ct * 16 + c;
    const float bvv = bv_l[col];
    #pragma unroll
    for (int rt = 0; rt < 4; ++rt)
      #pragma unroll
      for (int rr = 0; rr < 4; ++rr) {
        const int row = row0 + rt * 16 + g * 4 + rr;
        if (row < NN) agg[(size_t)row * 256 + col] = acc[rt][ct][rr] + sfac[row] * bvv;
      }
  }
}

// ---------------- per-node double layer-norm ----------------

__global__ __launch_bounds__(256) void k_norm(__bf16* __restrict__ hb,
                                              const float* __restrict__ agg,
                                              const float* __restrict__ aw,
                                              const float* __restrict__ ab,
                                              const float* __restrict__ lw,
                                              const float* __restrict__ lb) {
  const int lane = threadIdx.x & 63;
  const int wv = threadIdx.x >> 6;
  const int node = blockIdx.x * 4 + wv;
  const size_t base = (size_t)node * 256 + lane * 4;
  f32x4 x4 = *reinterpret_cast<const f32x4*>(agg + base);
  float x[4], y[4];
  float s = 0.0f;
  #pragma unroll
  for (int j = 0; j < 4; ++j) { x[j] = x4[j]; s += x[j]; }
  #pragma unroll
  for (int m = 1; m < 64; m <<= 1) s += __shfl_xor(s, m, 64);
  const float mean = s * (1.0f / 256.0f);
  float v = 0.0f;
  #pragma unroll
  for (int j = 0; j < 4; ++j) { float d = x[j] - mean; v += d * d; }
  #pragma unroll
  for (int m = 1; m < 64; m <<= 1) v += __shfl_xor(v, m, 64);
  const float rstd = rsqrtf(v * (1.0f / 256.0f) + 1e-5f);

  bf16x4 hv = *reinterpret_cast<const bf16x4*>(hb + base);
  float s2 = 0.0f;
  #pragma unroll
  for (int j = 0; j < 4; ++j) {
    const int k = lane * 4 + j;
    float hn = (x[j] - mean) * rstd * aw[k] + ab[k];
    y[j] = (float)hv[j] + hn;
    s2 += y[j];
  }
  #pragma unroll
  for (int m = 1; m < 64; m <<= 1) s2 += __shfl_xor(s2, m, 64);
  const float mean2 = s2 * (1.0f / 256.0f);
  float v2 = 0.0f;
  #pragma unroll
  for (int j = 0; j < 4; ++j) { float d = y[j] - mean2; v2 += d * d; }
  #pragma unroll
  for (int m = 1; m < 64; m <<= 1) v2 += __shfl_xor(v2, m, 64);
  const float rstd2 = rsqrtf(v2 * (1.0f / 256.0f) + 1e-5f);
  bf16x4 o;
  #pragma unroll
  for (int j = 0; j < 4; ++j) {
    const int k = lane * 4 + j;
    o[j] = (__bf16)((y[j] - mean2) * rstd2 * lw[k] + lb[k]);
  }
  *reinterpret_cast<bf16x4*>(hb + base) = o;
}

// ---------------- out = gelu(h @ out_w^T + out_b)  (64x64 wave tiles, rows split) ----------------

__global__ __launch_bounds__(256, 3) void k_out(const __bf16* __restrict__ hb,
                                                const __bf16* __restrict__ ow,
                                                const float* __restrict__ ob,
                                                float* __restrict__ out) {
  const int lane = threadIdx.x & 63;
  const int wv = threadIdx.x >> 6;
  const int c = lane & 15, g = lane >> 4;
  const int row0 = blockIdx.x * 256 + wv * 64;

  const __bf16* Ar[4];
  const __bf16* Bp[4];
  #pragma unroll
  for (int rt = 0; rt < 4; ++rt) {
    int r = row0 + rt * 16 + c; if (r >= NN) r = NN - 1;
    Ar[rt] = hb + (size_t)r * 256;
  }
  #pragma unroll
  for (int ct = 0; ct < 4; ++ct)
    Bp[ct] = ow + (size_t)(ct * 16 + c) * 256;

  f32x4 acc[4][4];
  #pragma unroll
  for (int rt = 0; rt < 4; ++rt)
    for (int ct = 0; ct < 4; ++ct)
      for (int r = 0; r < 4; ++r) acc[rt][ct][r] = 0.0f;

  for (int ks = 0; ks < 8; ++ks) {
    const int k = ks * 32 + g * 8;
    bf16x8 a[4], b[4];
    #pragma unroll
    for (int rt = 0; rt < 4; ++rt) a[rt] = ld8(Ar[rt] + k);
    #pragma unroll
    for (int ct = 0; ct < 4; ++ct) b[ct] = ld8(Bp[ct] + k);
    #pragma unroll
    for (int rt = 0; rt < 4; ++rt)
      #pragma unroll
      for (int ct = 0; ct < 4; ++ct)
        acc[rt][ct] = __builtin_amdgcn_mfma_f32_16x16x32_bf16(a[rt], b[ct], acc[rt][ct], 0, 0, 0);
  }
  #pragma unroll
  for (int ct = 0; ct < 4; ++ct) {
    const int col = ct * 16 + c;
    const float bv = ob[col];
    #pragma unroll
    for (int rt = 0; rt < 4; ++rt)
      #pragma unroll
      for (int rr = 0; rr < 4; ++rr) {
        const int row = row0 + rt * 16 + g * 4 + rr;
        if (row < NN) {
          float x = acc[rt][ct][rr] + bv;
          out[(size_t)row * 64 + col] = 0.5f * x * (1.0f + erff(x * 0.70710678118654752f));
        }
      }
  }
}

// ---------------- launcher ----------------

extern "C" void kernel_launch(void* const* d_in, const int* in_sizes, int n_in,
                              void* d_out, int out_size, void* d_ws, size_t ws_size,
                              hipStream_t stream) {
  (void)in_sizes; (void)n_in; (void)out_size; (void)ws_size;
  const float* nf   = (const float*)d_in[0];
  const float* mem  = (const float*)d_in[1];
  const int*   ei   = (const int*)d_in[2];
  const float* ef   = (const float*)d_in[3];
  const float* tim  = (const float*)d_in[4];
  const float* inw  = (const float*)d_in[5];
  const float* inb  = (const float*)d_in[6];
  const float* tew  = (const float*)d_in[7];
  const float* teph = (const float*)d_in[8];
  const float* wq   = (const float*)d_in[9];
  const float* wqb  = (const float*)d_in[10];
  const float* wk   = (const float*)d_in[11];
  const float* wkb  = (const float*)d_in[12];
  const float* wvw  = (const float*)d_in[13];
  const float* wvb  = (const float*)d_in[14];
  const float* alw  = (const float*)d_in[15];
  const float* alb  = (const float*)d_in[16];
  const float* lnw  = (const float*)d_in[17];
  const float* lnb  = (const float*)d_in[18];
  const float* ow   = (const float*)d_in[19];
  const float* ob   = (const float*)d_in[20];
  float* out = (float*)d_out;

  char* ws = (char*)d_ws;
  __bf16* hb    = (__bf16*)(ws + 0);            // N*256 bf16  = 25,600,000
  __bf16* aux   = (__bf16*)(ws + 25600000);     // E*96 bf16   = 38,400,000
  __bf16* Qn    = (__bf16*)(ws + 64000000);     // N*256 bf16  = 25,600,000
  __bf16* Kn    = (__bf16*)(ws + 89600000);     // N*256 bf16  = 25,600,000
  float*  agg   = (float*) (ws + 64000000);     // N*256 f32 (aliases Qn+Kn; disjoint in time)
  __bf16* maggH = (__bf16*)(ws + 115200000);    // N*256 bf16  = 25,600,000
  __bf16* maggX = (__bf16*)(ws + 140800000);    // N*96 bf16   =  9,600,000
  __bf16* G     = (__bf16*)(ws + 115200000);    // N*320 bf16 = 32,000,000 aliases maggH/X; disjoint in time
  float*  sfac  = (float*) (ws + 150400000);    // N f32
  float*  af    = (float*) (ws + 150600000);    // E f32
  int*    ddst  = (int*)   (ws + 151400000);    // E int
  int*    rowptr= (int*)   (ws + 152200000);    // (N+1) int
  int*    wp    = (int*)   (ws + 152400192);    // N int
  int*    bucket= (int*)   (ws + 152600192);    // E int
  float*  cq    = (float*) (ws + 153400192);    // 2*256 f32
  int*    bsum  = (int*)   (ws + 153402240);    // 196 int
  __bf16* cinw  = (__bf16*)(ws + 153403264);    // 131,072
  __bf16* cwq   = (__bf16*)(ws + 153534336);    // 278,528
  __bf16* cwk   = (__bf16*)(ws + 153812864);    // 344,064
  __bf16* cwv   = (__bf16*)(ws + 154156928);    // 344,064
  __bf16* cow   = (__bf16*)(ws + 154500992);    // 32,768
  __bf16* twk   = (__bf16*)(ws + 154533760);    // 98,304 -> end 154,632,064

  k_cvta<<<(565248 + 255) / 256, 256, 0, stream>>>(inw, wq, wk, wvw, ow,
                                                   cinw, cwq, cwk, cwv, cow);
  k_wt<<<(49152 + 255) / 256, 256, 0, stream>>>(cwk, twk);
  k_ddst<<<(EE + 255) / 256, 256, 0, stream>>>(ei, ddst);

  // CSR build (hierarchical scan)
  const int NB = (NN + 255) / 256;   // 196
  hipMemsetAsync(wp, 0, NN * 4, stream);
  k_hist<<<(EE + 255) / 256, 256, 0, stream>>>(ei, wp);
  k_blksum<<<NB, 256, 0, stream>>>(wp, bsum);
  k_scanb<<<1, 256, 0, stream>>>(bsum, NB);
  k_scanc<<<NB, 256, 0, stream>>>(wp, bsum, rowptr);
  k_fill<<<(EE + 255) / 256, 256, 0, stream>>>(ei, wp, bucket);

  k_auxef<<<EE / 4, 256, 0, stream>>>(ef, aux);
  k_cq2<<<2, 256, 0, stream>>>(wq, wqb, teph, cq);
  k_h0<<<(NN + 63) / 64, 256, 0, stream>>>(nf, mem, cinw, inb, hb);

  for (int l = 0; l < 2; ++l) {
    const __bf16* wq_l = cwq + (size_t)l * 256 * 272;
    const __bf16* wk_l = cwk + (size_t)l * 256 * 336;
    const __bf16* wv_l = cwv + (size_t)l * 256 * 336;
    k_auxte<<<EE * 16 / 256, 256, 0, stream>>>(tim, tew + l * 16, teph + l * 16, aux);
    k_qkn<<<(NN + 63) / 64, 256, 0, stream>>>(hb, wq_l, wk_l, cq + l * 256, wkb + l * 256, Qn, Kn);
    k_g<<<(NN + 63) / 64, 256, 0, stream>>>(Qn, twk + (size_t)l * 24576, G);
    k_score<<<EE / 64, 256, 0, stream>>>(aux, G, Qn, Kn, ei, ddst, af);
    k_magg<<<NN / 4, 256, 0, stream>>>(hb, aux, ei, rowptr, bucket, af, maggH, maggX, sfac);
    k_vgemm<<<(NN + 63) / 64, 256, 0, stream>>>(maggH, maggX, sfac, wv_l, wvb + l * 256, agg);
    k_norm<<<NN / 4, 256, 0, stream>>>(hb, agg, alw + l * 256, alb + l * 256,
                                       lnw + l * 256, lnb + l * 256);
  }
  k_out<<<(NN + 255) / 256, 256, 0, stream>>>(hb, cow, ob, out);
}